// Round 2
// baseline (2335.767 us; speedup 1.0000x reference)
//
#include <hip/hip_runtime.h>

typedef unsigned short u16;
typedef __bf16 bf16x8 __attribute__((ext_vector_type(8)));
typedef float f32x4 __attribute__((ext_vector_type(4)));

#define NB 4
#define NN 256
#define DD 128
#define RNN 262144   // NB*NN*NN

__device__ __forceinline__ u16 f2b(float f) {
    unsigned u = __builtin_bit_cast(unsigned, f);
    unsigned rb = ((u >> 16) & 1u) + 0x7FFFu;
    return (u16)((u + rb) >> 16);
}
__device__ __forceinline__ float b2f(u16 u) {
    return __builtin_bit_cast(float, ((unsigned)u) << 16);
}

__device__ __forceinline__ void glds16(const void* g, void* l) {
    __builtin_amdgcn_global_load_lds((const __attribute__((address_space(1))) void*)g,
                                     (__attribute__((address_space(3))) void*)l, 16, 0, 0);
}

// ---------------- weight prep: bf16 convert + transpose to [N][K] ----------------
__global__ void prep_weights(const float* __restrict__ Wqkv_e, const float* __restrict__ bqkv_e,
                             const float* __restrict__ We1a, const float* __restrict__ We1b,
                             const float* __restrict__ We2a, const float* __restrict__ We2b,
                             u16* wqT, u16* wv, float* bqp, float* bvp,
                             u16* we1aT, u16* we1bT, u16* we2aT, u16* we2bT) {
    int l = blockIdx.z, sec = blockIdx.y;
    int idx = blockIdx.x * 256 + threadIdx.x;
    if (sec == 0) {            // WqT[l][n*128+k] = Wqkv_e[l][k][qcol(n)]
        if (idx < 16384) {
            int n = idx >> 7, k = idx & 127;
            int col = (n >> 4) * 48 + (n & 15);
            wqT[l * 16384 + n * 128 + k] = f2b(Wqkv_e[l * 49152 + k * 384 + col]);
        }
    } else if (sec == 1) {     // Wv plain [k][c]
        if (idx < 16384) {
            int k = idx >> 7, c = idx & 127;
            int col = (c >> 4) * 48 + 32 + (c & 15);
            wv[l * 16384 + k * 128 + c] = f2b(Wqkv_e[l * 49152 + k * 384 + col]);
        }
        if (idx < 128) {
            bqp[l * 128 + idx] = bqkv_e[l * 384 + (idx >> 4) * 48 + (idx & 15)];
            bvp[l * 128 + idx] = bqkv_e[l * 384 + (idx >> 4) * 48 + 32 + (idx & 15)];
        }
    } else if (sec == 2) {     // We1aT [512 n][256 k] — only e/eT segments (K rows 0..255)
        if (idx < 131072) {
            int n = idx >> 8, k = idx & 255;
            we1aT[l * 131072 + n * 256 + k] = f2b(We1a[l * 262144 + k * 512 + n]);
        }
    } else if (sec == 3) {     // We1bT [128][512]
        if (idx < 65536) {
            int n = idx >> 9, k = idx & 511;
            we1bT[l * 65536 + n * 512 + k] = f2b(We1b[l * 65536 + k * 128 + n]);
        }
    } else if (sec == 4) {     // We2aT [512][128]
        if (idx < 65536) {
            int n = idx >> 7, k = idx & 127;
            we2aT[l * 65536 + n * 128 + k] = f2b(We2a[l * 65536 + k * 512 + n]);
        }
    } else {                   // We2bT [128][512]
        if (idx < 65536) {
            int n = idx >> 9, k = idx & 511;
            we2bT[l * 65536 + n * 512 + k] = f2b(We2b[l * 65536 + k * 128 + n]);
        }
    }
}

__global__ void init_e(const float4* __restrict__ src, ushort4* __restrict__ dst) {
    const long n4 = 8388608;  // 33.5M elems /4
    for (long i = (long)blockIdx.x * blockDim.x + threadIdx.x; i < n4; i += (long)gridDim.x * blockDim.x) {
        float4 v = src[i];
        ushort4 o;
        o.x = f2b(v.x); o.y = f2b(v.y); o.z = f2b(v.z); o.w = f2b(v.w);
        dst[i] = o;
    }
}

__global__ void init_n(const float* __restrict__ node, float* __restrict__ nf) {
    int i = blockIdx.x * 256 + threadIdx.x;
    if (i < 131072) nf[i] = node[i];
}

// ---------------- pre_node: preS[b,j,c] = n[b,j]·We1a_seg2[:,c]; preT[b,i,c] = n[b,i]·We1a_seg3[:,c]
__launch_bounds__(512)
__global__ void pre_node_kernel(const float* __restrict__ nf, const float* __restrict__ We1a,
                                float* __restrict__ preS, float* __restrict__ preT) {
    __shared__ float nr[128];
    int tid = threadIdx.x;
    int row = blockIdx.x;   // b*256 + n
    if (tid < 128) nr[tid] = nf[(long)row * 128 + tid];
    __syncthreads();
    int c = tid;            // 0..511
    float s = 0.f, t = 0.f;
    const float* Ws = We1a + (long)256 * 512 + c;   // seg2 rows 256..383
    const float* Wt = We1a + (long)384 * 512 + c;   // seg3 rows 384..511
    #pragma unroll 8
    for (int k = 0; k < 128; ++k) {
        float nv = nr[k];
        s += nv * Ws[k * 512];
        t += nv * Wt[k * 512];
    }
    preS[(long)row * 512 + c] = s;
    preT[(long)row * 512 + c] = t;
}

// ---------------- K1: qn/vn = n @ Wqkv_n (packed head-major cols) ----------------
__global__ void qkvn_kernel(const float* __restrict__ nf, const float* __restrict__ W,
                            const float* __restrict__ bias, float* __restrict__ qn, float* __restrict__ vn) {
    __shared__ float nr[128];
    int tid = threadIdx.x;
    int row = blockIdx.x;                // b*256+i
    if (tid < 128) nr[tid] = nf[(long)row * 128 + tid];
    __syncthreads();
    int c = tid & 127;
    bool isq = tid < 128;
    int col = (c >> 4) * 48 + (c & 15) + (isq ? 0 : 32);
    float a = bias[col];
    #pragma unroll 8
    for (int k = 0; k < 128; ++k) a += nr[k] * W[k * 384 + col];
    if (isq) qn[(long)row * 128 + c] = a;
    else     vn[(long)row * 128 + c] = a;
}

// ---------------- K2: scores[b,h,i,j] = scale*||qn+ e@Wq + bq||^2 ----------------
__launch_bounds__(256, 2)
__global__ void scores_kernel(const u16* __restrict__ ein, const u16* __restrict__ WqT,
                              const float* __restrict__ bqp, const float* __restrict__ qn,
                              float* __restrict__ scoresp) {
    __shared__ u16 As[128 * 64];
    __shared__ u16 Bs[128 * 64];
    int tid = threadIdx.x;
    int wid = tid >> 6, lane = tid & 63;
    int bid = blockIdx.x;
    int jhalf = bid & 1, bi = bid >> 1;
    int b = bi >> 8, i = bi & 255;
    int wr = wid >> 1, wc = wid & 1;   // 2x2 waves, wave=64 rows x 64 cols

    f32x4 acc[4][4];
    f32x4 z = {0.f, 0.f, 0.f, 0.f};
    #pragma unroll
    for (int m = 0; m < 4; ++m)
        #pragma unroll
        for (int n = 0; n < 4; ++n) acc[m][n] = z;

    const long arow0 = ((long)(b * NN + i) * NN + jhalf * 128);
    for (int kt = 0; kt < 2; ++kt) {
        int k0 = kt << 6;
        #pragma unroll
        for (int p = 0; p < 4; ++p) {
            int r = p * 32 + (tid >> 3);
            int ch = tid & 7;
            const u16* src = ein + (arow0 + r) * 128 + k0 + ((ch ^ (r & 7)) << 3);
            glds16(src, (char*)As + (p << 12) + (wid << 10));
            int n = p * 32 + (tid >> 3);
            const u16* bsrc = WqT + (long)n * 128 + k0 + ((ch ^ (n & 7)) << 3);
            glds16(bsrc, (char*)Bs + (p << 12) + (wid << 10));
        }
        __syncthreads();
        #pragma unroll
        for (int ks = 0; ks < 2; ++ks) {
            bf16x8 af[4], bfr[4];
            #pragma unroll
            for (int m = 0; m < 4; ++m) {
                int r = wr * 64 + m * 16 + (lane & 15);
                int ch = (ks * 4 + (lane >> 4)) ^ (r & 7);
                af[m] = *reinterpret_cast<const bf16x8*>(&As[r * 64 + ch * 8]);
            }
            #pragma unroll
            for (int n = 0; n < 4; ++n) {
                int c = wc * 64 + n * 16 + (lane & 15);
                int ch = (ks * 4 + (lane >> 4)) ^ (c & 7);
                bfr[n] = *reinterpret_cast<const bf16x8*>(&Bs[c * 64 + ch * 8]);
            }
            #pragma unroll
            for (int m = 0; m < 4; ++m)
                #pragma unroll
                for (int n = 0; n < 4; ++n)
                    acc[m][n] = __builtin_amdgcn_mfma_f32_16x16x32_bf16(af[m], bfr[n], acc[m][n], 0, 0, 0);
        }
        __syncthreads();
    }
    const float* qnb = qn + (long)(b * NN + i) * 128;
    #pragma unroll
    for (int m = 0; m < 4; ++m) {
        #pragma unroll
        for (int n = 0; n < 4; ++n) {
            int col = wc * 64 + n * 16 + (lane & 15);
            float add = bqp[col] + qnb[col];
            float sv[4];
            #pragma unroll
            for (int t = 0; t < 4; ++t) { float qv = acc[m][n][t] + add; sv[t] = qv * qv; }
            #pragma unroll
            for (int mk = 1; mk <= 8; mk <<= 1)
                #pragma unroll
                for (int t = 0; t < 4; ++t) sv[t] += __shfl_xor(sv[t], mk);
            if ((lane & 15) == 0) {
                int head = wc * 4 + n;
                int jb = jhalf * 128 + wr * 64 + m * 16 + ((lane >> 4) << 2);
                long sbase = ((long)(b * 8 + head) * 256 + i) * 256 + jb;
                #pragma unroll
                for (int t = 0; t < 4; ++t) scoresp[sbase + t] = sv[t] * 0.25f;
            }
        }
    }
}

// ---------------- K3: softmax + factored PV ----------------
__launch_bounds__(256)
__global__ void attn_pv_kernel(const float* __restrict__ scoresp, const u16* __restrict__ ein,
                               const float* __restrict__ vn, const u16* __restrict__ Wv,
                               const float* __restrict__ bvp, float* __restrict__ attn_o) {
    __shared__ float s_s[8 * 256];
    __shared__ float g_s[8 * 128];
    __shared__ float part[256];
    int tid = threadIdx.x;
    int b = blockIdx.x >> 8, i = blockIdx.x & 255;
    for (int v = tid; v < 2048; v += 256) {
        int h = v >> 8, j = v & 255;
        s_s[v] = scoresp[((long)(b * 8 + h) * 256 + i) * 256 + j];
    }
    __syncthreads();
    {   // softmax: 8 groups of 32 lanes, one head each
        int h = tid >> 5, lg = tid & 31;
        float vals[8], mx = -1e30f;
        #pragma unroll
        for (int t = 0; t < 8; ++t) { vals[t] = s_s[h * 256 + lg + t * 32]; mx = fmaxf(mx, vals[t]); }
        #pragma unroll
        for (int mk = 16; mk; mk >>= 1) mx = fmaxf(mx, __shfl_xor(mx, mk));
        float sum = 0.f;
        #pragma unroll
        for (int t = 0; t < 8; ++t) { vals[t] = __expf(vals[t] - mx); sum += vals[t]; }
        #pragma unroll
        for (int mk = 16; mk; mk >>= 1) sum += __shfl_xor(sum, mk);
        float inv = 1.f / sum;
        #pragma unroll
        for (int t = 0; t < 8; ++t) s_s[h * 256 + lg + t * 32] = vals[t] * inv;
    }
    __syncthreads();
    {   // g[h][k] = sum_j att[h][j]*e[b,i,j,k]
        int k = tid & 127, h0 = tid >> 7;  // 0/1
        const u16* erow = ein + ((long)(b * NN + i) * NN) * 128 + k;
        float a0 = 0, a1 = 0, a2 = 0, a3 = 0;
        for (int j = 0; j < 256; ++j) {
            float ev = b2f(erow[(long)j * 128]);
            a0 += s_s[(h0    ) * 256 + j] * ev;
            a1 += s_s[(h0 + 2) * 256 + j] * ev;
            a2 += s_s[(h0 + 4) * 256 + j] * ev;
            a3 += s_s[(h0 + 6) * 256 + j] * ev;
        }
        g_s[(h0    ) * 128 + k] = a0;
        g_s[(h0 + 2) * 128 + k] = a1;
        g_s[(h0 + 4) * 128 + k] = a2;
        g_s[(h0 + 6) * 128 + k] = a3;
    }
    __syncthreads();
    {   // out[c] = sum_j att*vn + sum_k g*Wv + bv
        int c = tid & 127, half = tid >> 7;
        int h = c >> 4;
        float a = 0.f;
        for (int j = half * 128; j < half * 128 + 128; ++j)
            a += s_s[h * 256 + j] * vn[((long)(b * NN + j)) * 128 + c];
        for (int k = half * 64; k < half * 64 + 64; ++k)
            a += g_s[h * 128 + k] * b2f(Wv[k * 128 + c]);
        part[tid] = a;
    }
    __syncthreads();
    if (tid < 128)
        attn_o[((long)(b * NN + i)) * 128 + tid] = part[tid] + part[128 + tid] + bvp[tid];
}

// ---------------- K4: node path (Wo proj + LN1 + FFN + LN2) ----------------
__launch_bounds__(256)
__global__ void node_kernel(const float* __restrict__ attn_o, float* __restrict__ nf,
                            const float* __restrict__ Wo, const float* __restrict__ bo,
                            const float* __restrict__ Wn1, const float* __restrict__ bn1,
                            const float* __restrict__ Wn2, const float* __restrict__ bn2,
                            const float* __restrict__ g1, const float* __restrict__ b1,
                            const float* __restrict__ g2, const float* __restrict__ b2) {
    __shared__ float ao[128], nr[128], n1[128], hb[512];
    __shared__ float red[8];
    int tid = threadIdx.x;
    int wid = tid >> 6, lane = tid & 63;
    long base = (long)blockIdx.x * 128;
    if (tid < 128) { ao[tid] = attn_o[base + tid]; nr[tid] = nf[base + tid]; }
    __syncthreads();
    float x = 0.f;
    if (tid < 128) {
        float a = bo[tid];
        #pragma unroll 8
        for (int k = 0; k < 128; ++k) a += ao[k] * Wo[k * 128 + tid];
        x = nr[tid] + a;
    }
    float s = (tid < 128) ? x : 0.f, q = (tid < 128) ? x * x : 0.f;
    #pragma unroll
    for (int mk = 1; mk <= 32; mk <<= 1) { s += __shfl_xor(s, mk); q += __shfl_xor(q, mk); }
    if (lane == 0) { red[wid * 2] = s; red[wid * 2 + 1] = q; }
    __syncthreads();
    float sum = red[0] + red[2] + red[4] + red[6];
    float sq  = red[1] + red[3] + red[5] + red[7];
    float mean = sum * (1.f / 128.f);
    float var = sq * (1.f / 128.f) - mean * mean;
    float rs = rsqrtf(var + 1e-5f);
    __syncthreads();
    if (tid < 128) n1[tid] = (x - mean) * rs * g1[tid] + b1[tid];
    __syncthreads();
    for (int c = tid; c < 512; c += 256) {
        float a = bn1[c];
        #pragma unroll 8
        for (int k = 0; k < 128; ++k) a += n1[k] * Wn1[k * 512 + c];
        hb[c] = a > 0.f ? a : 0.f;
    }
    __syncthreads();
    float y = 0.f;
    if (tid < 128) {
        float a = bn2[tid];
        #pragma unroll 8
        for (int k = 0; k < 512; ++k) a += hb[k] * Wn2[k * 128 + tid];
        y = n1[tid] + a;
    }
    float s2 = (tid < 128) ? y : 0.f, q2 = (tid < 128) ? y * y : 0.f;
    #pragma unroll
    for (int mk = 1; mk <= 32; mk <<= 1) { s2 += __shfl_xor(s2, mk); q2 += __shfl_xor(q2, mk); }
    if (lane == 0) { red[wid * 2] = s2; red[wid * 2 + 1] = q2; }
    __syncthreads();
    sum = red[0] + red[2] + red[4] + red[6];
    sq  = red[1] + red[3] + red[5] + red[7];
    mean = sum * (1.f / 128.f);
    var = sq * (1.f / 128.f) - mean * mean;
    rs = rsqrtf(var + 1e-5f);
    if (tid < 128) {
        float o = (y - mean) * rs * g2[tid] + b2[tid];
        nf[base + tid] = o;
    }
}

// ---------------- gemm_relu: H = relu(A @ W^T(N,K) + bias [+preS+preT]), A = cat2 or plain ----------------
__launch_bounds__(512, 2)
__global__ void gemm_relu_kernel(const u16* __restrict__ WT, const float* __restrict__ bias,
                                 u16* __restrict__ Hout, const u16* __restrict__ Aplain,
                                 const u16* __restrict__ ein,
                                 const float* __restrict__ preS, const float* __restrict__ preT,
                                 int K, int cat_mode, long chunk_base) {
    __shared__ u16 As[128 * 64];
    __shared__ u16 Bs[256 * 64];
    int tid = threadIdx.x;
    int wid = tid >> 6, lane = tid & 63;
    long row0 = chunk_base + (long)blockIdx.x * 128;
    int ncol0 = blockIdx.y * 256;
    int wr = wid >> 2, wc = wid & 3;   // 2x4 waves: wave = 64 rows x 64 cols

    f32x4 acc[4][4];
    f32x4 z = {0.f, 0.f, 0.f, 0.f};
    #pragma unroll
    for (int m = 0; m < 4; ++m)
        #pragma unroll
        for (int n = 0; n < 4; ++n) acc[m][n] = z;

    int KT = K >> 6;
    for (int kt = 0; kt < KT; ++kt) {
        int k0 = kt << 6;
        #pragma unroll
        for (int p = 0; p < 2; ++p) {      // A: 128 rows x 64k
            int r = p * 64 + (tid >> 3);
            int ch = tid & 7;
            const u16* src;
            if (cat_mode) {
                long gr = row0 + r;
                int b = (int)(gr >> 16);
                int rem = (int)(gr & 65535);
                int i = rem >> 8, j = rem & 255;
                int seg = k0 >> 7;         // 0: e(i,j)   1: e(j,i)
                int off = (k0 & 127) + ((ch ^ (r & 7)) << 3);
                long ridx = seg == 0 ? (long)(b * NN + i) * NN + j
                                     : (long)(b * NN + j) * NN + i;
                src = ein + ridx * DD + off;
            } else {
                src = Aplain + (row0 + r) * K + k0 + ((ch ^ (r & 7)) << 3);
            }
            glds16(src, (char*)As + (p << 13) + (wid << 10));
        }
        #pragma unroll
        for (int qq = 0; qq < 4; ++qq) {   // B: 256 n x 64k
            int n = qq * 64 + (tid >> 3);
            int ch = tid & 7;
            const u16* src = WT + (long)(ncol0 + n) * K + k0 + ((ch ^ (n & 7)) << 3);
            glds16(src, (char*)Bs + (qq << 13) + (wid << 10));
        }
        __syncthreads();
        #pragma unroll
        for (int ks = 0; ks < 2; ++ks) {
            bf16x8 af[4], bfr[4];
            #pragma unroll
            for (int m = 0; m < 4; ++m) {
                int r = wr * 64 + m * 16 + (lane & 15);
                int ch = (ks * 4 + (lane >> 4)) ^ (r & 7);
                af[m] = *reinterpret_cast<const bf16x8*>(&As[r * 64 + ch * 8]);
            }
            #pragma unroll
            for (int n = 0; n < 4; ++n) {
                int c = wc * 64 + n * 16 + (lane & 15);
                int ch = (ks * 4 + (lane >> 4)) ^ (c & 7);
                bfr[n] = *reinterpret_cast<const bf16x8*>(&Bs[c * 64 + ch * 8]);
            }
            #pragma unroll
            for (int m = 0; m < 4; ++m)
                #pragma unroll
                for (int n = 0; n < 4; ++n)
                    acc[m][n] = __builtin_amdgcn_mfma_f32_16x16x32_bf16(af[m], bfr[n], acc[m][n], 0, 0, 0);
        }
        __syncthreads();
    }
    long hrow0 = (long)blockIdx.x * 128;   // chunk-local h rows
    if (cat_mode) {
        int b = (int)(row0 >> 16);
        int rem0 = (int)(row0 & 65535);
        int i = rem0 >> 8, j0 = rem0 & 255;
        const float* pT = preT + ((long)(b * NN + i)) * 512;
        const float* pS = preS + ((long)(b * NN + j0)) * 512;
        #pragma unroll
        for (int m = 0; m < 4; ++m) {
            int r = wr * 64 + m * 16 + ((lane >> 4) << 2);
            #pragma unroll
            for (int n = 0; n < 4; ++n) {
                int c = ncol0 + wc * 64 + n * 16 + (lane & 15);
                float bb = bias[c] + pT[c];
                #pragma unroll
                for (int t = 0; t < 4; ++t) {
                    float v = acc[m][n][t] + bb + pS[(long)(r + t) * 512 + c];
                    v = v > 0.f ? v : 0.f;
                    Hout[(hrow0 + r + t) * 512 + c] = f2b(v);
                }
            }
        }
    } else {
        #pragma unroll
        for (int m = 0; m < 4; ++m) {
            int r = wr * 64 + m * 16 + ((lane >> 4) << 2);
            #pragma unroll
            for (int n = 0; n < 4; ++n) {
                int c = ncol0 + wc * 64 + n * 16 + (lane & 15);
                float bb = bias[c];
                #pragma unroll
                for (int t = 0; t < 4; ++t) {
                    float v = acc[m][n][t] + bb;
                    v = v > 0.f ? v : 0.f;
                    Hout[(hrow0 + r + t) * 512 + c] = f2b(v);
                }
            }
        }
    }
}

// ---------------- gemm_ln: e_dst = LN(e_res + H @ WT(128,512) + bias) ----------------
__launch_bounds__(512, 2)
__global__ void gemm_ln_kernel(const u16* __restrict__ Hin, const u16* __restrict__ WT,
                               const float* __restrict__ bias, const u16* __restrict__ e_res,
                               const float* __restrict__ lng, const float* __restrict__ lnb,
                               u16* __restrict__ e_dst, long chunk_base) {
    __shared__ u16 As[128 * 64];
    __shared__ u16 Bs[128 * 64];
    __shared__ float psum[128 * 4];
    __shared__ float psq[128 * 4];
    int tid = threadIdx.x;
    int wid = tid >> 6, lane = tid & 63;
    long hrow0 = (long)blockIdx.x * 128;
    long grow0 = chunk_base + hrow0;
    int wr = wid >> 2, wc = wid & 3;   // wave = 64 rows x 32 cols

    f32x4 acc[4][2];
    f32x4 z = {0.f, 0.f, 0.f, 0.f};
    #pragma unroll
    for (int m = 0; m < 4; ++m) { acc[m][0] = z; acc[m][1] = z; }

    for (int kt = 0; kt < 8; ++kt) {
        int k0 = kt << 6;
        #pragma unroll
        for (int p = 0; p < 2; ++p) {
            int r = p * 64 + (tid >> 3);
            int ch = tid & 7;
            const u16* src = Hin + (hrow0 + r) * 512 + k0 + ((ch ^ (r & 7)) << 3);
            glds16(src, (char*)As + (p << 13) + (wid << 10));
            int n = p * 64 + (tid >> 3);
            const u16* bsrc = WT + (long)n * 512 + k0 + ((ch ^ (n & 7)) << 3);
            glds16(bsrc, (char*)Bs + (p << 13) + (wid << 10));
        }
        __syncthreads();
        #pragma unroll
        for (int ks = 0; ks < 2; ++ks) {
            bf16x8 af[4], bfr[2];
            #pragma unroll
            for (int m = 0; m < 4; ++m) {
                int r = wr * 64 + m * 16 + (lane & 15);
                int ch = (ks * 4 + (lane >> 4)) ^ (r & 7);
                af[m] = *reinterpret_cast<const bf16x8*>(&As[r * 64 + ch * 8]);
            }
            #pragma unroll
            for (int n = 0; n < 2; ++n) {
                int c = wc * 32 + n * 16 + (lane & 15);
                int ch = (ks * 4 + (lane >> 4)) ^ (c & 7);
                bfr[n] = *reinterpret_cast<const bf16x8*>(&Bs[c * 64 + ch * 8]);
            }
            #pragma unroll
            for (int m = 0; m < 4; ++m)
                #pragma unroll
                for (int n = 0; n < 2; ++n)
                    acc[m][n] = __builtin_amdgcn_mfma_f32_16x16x32_bf16(af[m], bfr[n], acc[m][n], 0, 0, 0);
        }
        __syncthreads();
    }
    // phase1: x = acc + bias + residual; per-row partial sums over this wave's 32 cols
    #pragma unroll
    for (int m = 0; m < 4; ++m) {
        float sv[4], qv[4];
        #pragma unroll
        for (int t = 0; t < 4; ++t) { sv[t] = 0.f; qv[t] = 0.f; }
        #pragma unroll
        for (int n = 0; n < 2; ++n) {
            int col = wc * 32 + n * 16 + (lane & 15);
            float bb = bias[col];
            #pragma unroll
            for (int t = 0; t < 4; ++t) {
                long row = wr * 64 + m * 16 + ((lane >> 4) << 2) + t;
                float xv = acc[m][n][t] + bb + b2f(e_res[(grow0 + row) * 128 + col]);
                acc[m][n][t] = xv;
                sv[t] += xv;
                qv[t] += xv * xv;
            }
        }
        #pragma unroll
        for (int mk = 1; mk <= 8; mk <<= 1)
            #pragma unroll
            for (int t = 0; t < 4; ++t) { sv[t] += __shfl_xor(sv[t], mk); qv[t] += __shfl_xor(qv[t], mk); }
        if ((lane & 15) == 0) {
            #pragma unroll
            for (int t = 0; t < 4; ++t) {
                int row = wr * 64 + m * 16 + ((lane >> 4) << 2) + t;
                psum[row * 4 + wc] = sv[t];
                psq[row * 4 + wc] = qv[t];
            }
        }
    }
    __syncthreads();
    // phase2: finish LN and store
    #pragma unroll
    for (int m = 0; m < 4; ++m) {
        #pragma unroll
        for (int t = 0; t < 4; ++t) {
            int row = wr * 64 + m * 16 + ((lane >> 4) << 2) + t;
            float sum = psum[row * 4] + psum[row * 4 + 1] + psum[row * 4 + 2] + psum[row * 4 + 3];
            float sq  = psq[row * 4] + psq[row * 4 + 1] + psq[row * 4 + 2] + psq[row * 4 + 3];
            float mean = sum * (1.f / 128.f);
            float var = sq * (1.f / 128.f) - mean * mean;
            float rs = rsqrtf(var + 1e-5f);
            #pragma unroll
            for (int n = 0; n < 2; ++n) {
                int col = wc * 32 + n * 16 + (lane & 15);
                float o = (acc[m][n][t] - mean) * rs * lng[col] + lnb[col];
                e_dst[(grow0 + row) * 128 + col] = f2b(o);
            }
        }
    }
}

extern "C" void kernel_launch(void* const* d_in, const int* in_sizes, int n_in,
                              void* d_out, int out_size, void* d_ws, size_t ws_size,
                              hipStream_t stream) {
    (void)in_sizes; (void)n_in; (void)out_size;
    const float* node   = (const float*)d_in[0];
    const float* edge   = (const float*)d_in[1];
    const float* Wqkv_n = (const float*)d_in[2];
    const float* bqkv_n = (const float*)d_in[3];
    const float* Wqkv_e = (const float*)d_in[4];
    const float* bqkv_e = (const float*)d_in[5];
    const float* Wo     = (const float*)d_in[6];
    const float* bo     = (const float*)d_in[7];
    const float* Wn1    = (const float*)d_in[8];
    const float* bn1    = (const float*)d_in[9];
    const float* Wn2    = (const float*)d_in[10];
    const float* bn2    = (const float*)d_in[11];
    const float* ln1n_g = (const float*)d_in[12];
    const float* ln1n_b = (const float*)d_in[13];
    const float* ln2n_g = (const float*)d_in[14];
    const float* ln2n_b = (const float*)d_in[15];
    const float* We1a   = (const float*)d_in[16];
    const float* be1a   = (const float*)d_in[17];
    const float* We1b   = (const float*)d_in[18];
    const float* be1b   = (const float*)d_in[19];
    const float* We2a   = (const float*)d_in[20];
    const float* be2a   = (const float*)d_in[21];
    const float* We2b   = (const float*)d_in[22];
    const float* be2b   = (const float*)d_in[23];
    const float* ln1e_g = (const float*)d_in[24];
    const float* ln1e_b = (const float*)d_in[25];
    const float* ln2e_g = (const float*)d_in[26];
    const float* ln2e_b = (const float*)d_in[27];

    size_t off = 0;
    char* wsb = (char*)d_ws;
    auto alloc = [&](size_t bytes) -> void* {
        void* p = wsb + off;
        off = (off + bytes + 255) & ~(size_t)255;
        return p;
    };
    u16* eb0      = (u16*)alloc((size_t)RNN * 128 * 2);
    u16* eb1      = (u16*)alloc((size_t)RNN * 128 * 2);
    float* scoresp= (float*)alloc((size_t)2097152 * 4);
    float* qn     = (float*)alloc(131072 * 4);
    float* vn     = (float*)alloc(131072 * 4);
    float* attn_o = (float*)alloc(131072 * 4);
    float* nf     = (float*)alloc(131072 * 4);
    float* preS   = (float*)alloc((size_t)1024 * 512 * 4);
    float* preT   = (float*)alloc((size_t)1024 * 512 * 4);
    u16* wqT      = (u16*)alloc(3 * 16384 * 2);
    u16* wv       = (u16*)alloc(3 * 16384 * 2);
    float* bqp    = (float*)alloc(3 * 128 * 4);
    float* bvp    = (float*)alloc(3 * 128 * 4);
    u16* we1aT    = (u16*)alloc(3 * 131072ull * 2);
    u16* we1bT    = (u16*)alloc(3 * 65536 * 2);
    u16* we2aT    = (u16*)alloc(3 * 65536 * 2);
    u16* we2bT    = (u16*)alloc(3 * 65536 * 2);
    size_t remain = (ws_size > off) ? (ws_size - off) : 0;
    long chunk_rows = (long)(remain / 1024);   // h row = 512 * 2B
    if (chunk_rows > 32768) chunk_rows = 32768;  // keep hbuf (32MB) L3-resident
    chunk_rows &= ~127L;
    if (chunk_rows < 128) chunk_rows = 128;
    u16* hbuf = (u16*)alloc((size_t)chunk_rows * 1024);

    {
        dim3 g(1024, 6, 3);
        prep_weights<<<g, 256, 0, stream>>>(Wqkv_e, bqkv_e, We1a, We1b, We2a, We2b,
                                            wqT, wv, bqp, bvp, we1aT, we1bT, we2aT, we2bT);
    }
    init_e<<<2048, 256, 0, stream>>>((const float4*)edge, (ushort4*)eb0);
    init_n<<<512, 256, 0, stream>>>(node, nf);

    for (int l = 0; l < 3; ++l) {
        u16* ein  = (l & 1) ? eb1 : eb0;
        u16* eout = (l & 1) ? eb0 : eb1;
        qkvn_kernel<<<1024, 256, 0, stream>>>(nf, Wqkv_n + l * 49152, bqkv_n + l * 384, qn, vn);
        scores_kernel<<<2048, 256, 0, stream>>>(ein, wqT + l * 16384, bqp + l * 128, qn, scoresp);
        attn_pv_kernel<<<1024, 256, 0, stream>>>(scoresp, ein, vn, wv + l * 16384, bvp + l * 128, attn_o);
        node_kernel<<<1024, 256, 0, stream>>>(attn_o, nf,
                                              Wo + l * 16384, bo + l * 128,
                                              Wn1 + l * 65536, bn1 + l * 512,
                                              Wn2 + l * 65536, bn2 + l * 128,
                                              ln1n_g + l * 128, ln1n_b + l * 128,
                                              ln2n_g + l * 128, ln2n_b + l * 128);
        pre_node_kernel<<<1024, 512, 0, stream>>>(nf, We1a + (size_t)l * 262144, preS, preT);
        for (long base = 0; base < RNN; base += chunk_rows) {
            long rows_c = RNN - base;
            if (rows_c > chunk_rows) rows_c = chunk_rows;
            dim3 gr2((unsigned)(rows_c / 128), 2);
            unsigned gr1 = (unsigned)(rows_c / 128);
            gemm_relu_kernel<<<gr2, 512, 0, stream>>>(we1aT + l * 131072, be1a + l * 512, hbuf,
                                                      nullptr, ein, preS, preT, 256, 1, base);
            gemm_ln_kernel<<<gr1, 512, 0, stream>>>(hbuf, we1bT + l * 65536, be1b + l * 128,
                                                    ein, ln1e_g + l * 128, ln1e_b + l * 128, eout, base);
            gemm_relu_kernel<<<gr2, 512, 0, stream>>>(we2aT + l * 65536, be2a + l * 512, hbuf,
                                                      eout, nullptr, nullptr, nullptr, 128, 0, base);
            gemm_ln_kernel<<<gr1, 512, 0, stream>>>(hbuf, we2bT + l * 65536, be2b + l * 128,
                                                    eout, ln2e_g + l * 128, ln2e_b + l * 128, eout, base);
        }
    }
    hipMemcpyAsync(d_out, nf, 131072 * sizeof(float), hipMemcpyDeviceToDevice, stream);
}

// Round 3
// 2171.037 us; speedup vs baseline: 1.0759x; 1.0759x over previous
//
#include <hip/hip_runtime.h>

typedef unsigned short u16;
typedef __bf16 bf16x8 __attribute__((ext_vector_type(8)));
typedef float f32x4 __attribute__((ext_vector_type(4)));

#define NB 4
#define NN 256
#define DD 128
#define RNN 262144   // NB*NN*NN

__device__ __forceinline__ u16 f2b(float f) {
    unsigned u = __builtin_bit_cast(unsigned, f);
    unsigned rb = ((u >> 16) & 1u) + 0x7FFFu;
    return (u16)((u + rb) >> 16);
}
__device__ __forceinline__ float b2f(u16 u) {
    return __builtin_bit_cast(float, ((unsigned)u) << 16);
}

__device__ __forceinline__ void glds16(const void* g, void* l) {
    __builtin_amdgcn_global_load_lds((const __attribute__((address_space(1))) void*)g,
                                     (__attribute__((address_space(3))) void*)l, 16, 0, 0);
}

// ---------------- weight prep: bf16 convert + transpose to [N][K] ----------------
__global__ void prep_weights(const float* __restrict__ Wqkv_e, const float* __restrict__ bqkv_e,
                             const float* __restrict__ We1a, const float* __restrict__ We1b,
                             const float* __restrict__ We2a, const float* __restrict__ We2b,
                             u16* wqT, u16* wv, float* bqp, float* bvp,
                             u16* we1aT, u16* we1bT, u16* we2aT, u16* we2bT) {
    int l = blockIdx.z, sec = blockIdx.y;
    int idx = blockIdx.x * 256 + threadIdx.x;
    if (sec == 0) {            // WqT[l][n*128+k] = Wqkv_e[l][k][qcol(n)]
        if (idx < 16384) {
            int n = idx >> 7, k = idx & 127;
            int col = (n >> 4) * 48 + (n & 15);
            wqT[l * 16384 + n * 128 + k] = f2b(Wqkv_e[l * 49152 + k * 384 + col]);
        }
    } else if (sec == 1) {     // Wv plain [k][c]
        if (idx < 16384) {
            int k = idx >> 7, c = idx & 127;
            int col = (c >> 4) * 48 + 32 + (c & 15);
            wv[l * 16384 + k * 128 + c] = f2b(Wqkv_e[l * 49152 + k * 384 + col]);
        }
        if (idx < 128) {
            bqp[l * 128 + idx] = bqkv_e[l * 384 + (idx >> 4) * 48 + (idx & 15)];
            bvp[l * 128 + idx] = bqkv_e[l * 384 + (idx >> 4) * 48 + 32 + (idx & 15)];
        }
    } else if (sec == 2) {     // We1aT [512 n][256 k] — only e/eT segments (K rows 0..255)
        if (idx < 131072) {
            int n = idx >> 8, k = idx & 255;
            we1aT[l * 131072 + n * 256 + k] = f2b(We1a[l * 262144 + k * 512 + n]);
        }
    } else if (sec == 3) {     // We1bT [128][512]
        if (idx < 65536) {
            int n = idx >> 9, k = idx & 511;
            we1bT[l * 65536 + n * 512 + k] = f2b(We1b[l * 65536 + k * 128 + n]);
        }
    } else if (sec == 4) {     // We2aT [512][128]
        if (idx < 65536) {
            int n = idx >> 7, k = idx & 127;
            we2aT[l * 65536 + n * 128 + k] = f2b(We2a[l * 65536 + k * 512 + n]);
        }
    } else {                   // We2bT [128][512]
        if (idx < 65536) {
            int n = idx >> 9, k = idx & 511;
            we2bT[l * 65536 + n * 512 + k] = f2b(We2b[l * 65536 + k * 128 + n]);
        }
    }
}

__global__ void init_e(const float4* __restrict__ src, ushort4* __restrict__ dst) {
    const long n4 = 8388608;  // 33.5M elems /4
    for (long i = (long)blockIdx.x * blockDim.x + threadIdx.x; i < n4; i += (long)gridDim.x * blockDim.x) {
        float4 v = src[i];
        ushort4 o;
        o.x = f2b(v.x); o.y = f2b(v.y); o.z = f2b(v.z); o.w = f2b(v.w);
        dst[i] = o;
    }
}

__global__ void init_n(const float* __restrict__ node, float* __restrict__ nf) {
    int i = blockIdx.x * 256 + threadIdx.x;
    if (i < 131072) nf[i] = node[i];
}

// ---------------- pre_node: preS[b,j,c] = n[b,j]·We1a_seg2[:,c]; preT[b,i,c] = n[b,i]·We1a_seg3[:,c]
__launch_bounds__(512)
__global__ void pre_node_kernel(const float* __restrict__ nf, const float* __restrict__ We1a,
                                float* __restrict__ preS, float* __restrict__ preT) {
    __shared__ float nr[128];
    int tid = threadIdx.x;
    int row = blockIdx.x;   // b*256 + n
    if (tid < 128) nr[tid] = nf[(long)row * 128 + tid];
    __syncthreads();
    int c = tid;            // 0..511
    float s = 0.f, t = 0.f;
    const float* Ws = We1a + (long)256 * 512 + c;   // seg2 rows 256..383
    const float* Wt = We1a + (long)384 * 512 + c;   // seg3 rows 384..511
    #pragma unroll 8
    for (int k = 0; k < 128; ++k) {
        float nv = nr[k];
        s += nv * Ws[k * 512];
        t += nv * Wt[k * 512];
    }
    preS[(long)row * 512 + c] = s;
    preT[(long)row * 512 + c] = t;
}

// ---------------- K1: qn/vn = n @ Wqkv_n (packed head-major cols) ----------------
__global__ void qkvn_kernel(const float* __restrict__ nf, const float* __restrict__ W,
                            const float* __restrict__ bias, float* __restrict__ qn, float* __restrict__ vn) {
    __shared__ float nr[128];
    int tid = threadIdx.x;
    int row = blockIdx.x;                // b*256+i
    if (tid < 128) nr[tid] = nf[(long)row * 128 + tid];
    __syncthreads();
    int c = tid & 127;
    bool isq = tid < 128;
    int col = (c >> 4) * 48 + (c & 15) + (isq ? 0 : 32);
    float a = bias[col];
    #pragma unroll 8
    for (int k = 0; k < 128; ++k) a += nr[k] * W[k * 384 + col];
    if (isq) qn[(long)row * 128 + c] = a;
    else     vn[(long)row * 128 + c] = a;
}

// ---------------- K2: scores[b,h,i,j] = scale*||qn+ e@Wq + bq||^2 ----------------
__launch_bounds__(256, 2)
__global__ void scores_kernel(const u16* __restrict__ ein, const u16* __restrict__ WqT,
                              const float* __restrict__ bqp, const float* __restrict__ qn,
                              float* __restrict__ scoresp) {
    __shared__ u16 As[128 * 64];
    __shared__ u16 Bs[128 * 64];
    int tid = threadIdx.x;
    int wid = tid >> 6, lane = tid & 63;
    int bid = blockIdx.x;
    int jhalf = bid & 1, bi = bid >> 1;
    int b = bi >> 8, i = bi & 255;
    int wr = wid >> 1, wc = wid & 1;   // 2x2 waves, wave=64 rows x 64 cols

    f32x4 acc[4][4];
    f32x4 z = {0.f, 0.f, 0.f, 0.f};
    #pragma unroll
    for (int m = 0; m < 4; ++m)
        #pragma unroll
        for (int n = 0; n < 4; ++n) acc[m][n] = z;

    const long arow0 = ((long)(b * NN + i) * NN + jhalf * 128);
    for (int kt = 0; kt < 2; ++kt) {
        int k0 = kt << 6;
        #pragma unroll
        for (int p = 0; p < 4; ++p) {
            int r = p * 32 + (tid >> 3);
            int ch = tid & 7;
            const u16* src = ein + (arow0 + r) * 128 + k0 + ((ch ^ (r & 7)) << 3);
            glds16(src, (char*)As + (p << 12) + (wid << 10));
            int n = p * 32 + (tid >> 3);
            const u16* bsrc = WqT + (long)n * 128 + k0 + ((ch ^ (n & 7)) << 3);
            glds16(bsrc, (char*)Bs + (p << 12) + (wid << 10));
        }
        __syncthreads();
        #pragma unroll
        for (int ks = 0; ks < 2; ++ks) {
            bf16x8 af[4], bfr[4];
            #pragma unroll
            for (int m = 0; m < 4; ++m) {
                int r = wr * 64 + m * 16 + (lane & 15);
                int ch = (ks * 4 + (lane >> 4)) ^ (r & 7);
                af[m] = *reinterpret_cast<const bf16x8*>(&As[r * 64 + ch * 8]);
            }
            #pragma unroll
            for (int n = 0; n < 4; ++n) {
                int c = wc * 64 + n * 16 + (lane & 15);
                int ch = (ks * 4 + (lane >> 4)) ^ (c & 7);
                bfr[n] = *reinterpret_cast<const bf16x8*>(&Bs[c * 64 + ch * 8]);
            }
            #pragma unroll
            for (int m = 0; m < 4; ++m)
                #pragma unroll
                for (int n = 0; n < 4; ++n)
                    acc[m][n] = __builtin_amdgcn_mfma_f32_16x16x32_bf16(af[m], bfr[n], acc[m][n], 0, 0, 0);
        }
        __syncthreads();
    }
    const float* qnb = qn + (long)(b * NN + i) * 128;
    #pragma unroll
    for (int m = 0; m < 4; ++m) {
        #pragma unroll
        for (int n = 0; n < 4; ++n) {
            int col = wc * 64 + n * 16 + (lane & 15);
            float add = bqp[col] + qnb[col];
            float sv[4];
            #pragma unroll
            for (int t = 0; t < 4; ++t) { float qv = acc[m][n][t] + add; sv[t] = qv * qv; }
            #pragma unroll
            for (int mk = 1; mk <= 8; mk <<= 1)
                #pragma unroll
                for (int t = 0; t < 4; ++t) sv[t] += __shfl_xor(sv[t], mk);
            if ((lane & 15) == 0) {
                int head = wc * 4 + n;
                int jb = jhalf * 128 + wr * 64 + m * 16 + ((lane >> 4) << 2);
                long sbase = ((long)(b * 8 + head) * 256 + i) * 256 + jb;
                #pragma unroll
                for (int t = 0; t < 4; ++t) scoresp[sbase + t] = sv[t] * 0.25f;
            }
        }
    }
}

// ---------------- K3: softmax + factored PV ----------------
__launch_bounds__(256)
__global__ void attn_pv_kernel(const float* __restrict__ scoresp, const u16* __restrict__ ein,
                               const float* __restrict__ vn, const u16* __restrict__ Wv,
                               const float* __restrict__ bvp, float* __restrict__ attn_o) {
    __shared__ float s_s[8 * 256];
    __shared__ float g_s[8 * 128];
    __shared__ float part[256];
    int tid = threadIdx.x;
    int b = blockIdx.x >> 8, i = blockIdx.x & 255;
    for (int v = tid; v < 2048; v += 256) {
        int h = v >> 8, j = v & 255;
        s_s[v] = scoresp[((long)(b * 8 + h) * 256 + i) * 256 + j];
    }
    __syncthreads();
    {   // softmax: 8 groups of 32 lanes, one head each
        int h = tid >> 5, lg = tid & 31;
        float vals[8], mx = -1e30f;
        #pragma unroll
        for (int t = 0; t < 8; ++t) { vals[t] = s_s[h * 256 + lg + t * 32]; mx = fmaxf(mx, vals[t]); }
        #pragma unroll
        for (int mk = 16; mk; mk >>= 1) mx = fmaxf(mx, __shfl_xor(mx, mk));
        float sum = 0.f;
        #pragma unroll
        for (int t = 0; t < 8; ++t) { vals[t] = __expf(vals[t] - mx); sum += vals[t]; }
        #pragma unroll
        for (int mk = 16; mk; mk >>= 1) sum += __shfl_xor(sum, mk);
        float inv = 1.f / sum;
        #pragma unroll
        for (int t = 0; t < 8; ++t) s_s[h * 256 + lg + t * 32] = vals[t] * inv;
    }
    __syncthreads();
    {   // g[h][k] = sum_j att[h][j]*e[b,i,j,k]
        int k = tid & 127, h0 = tid >> 7;  // 0/1
        const u16* erow = ein + ((long)(b * NN + i) * NN) * 128 + k;
        float a0 = 0, a1 = 0, a2 = 0, a3 = 0;
        for (int j = 0; j < 256; ++j) {
            float ev = b2f(erow[(long)j * 128]);
            a0 += s_s[(h0    ) * 256 + j] * ev;
            a1 += s_s[(h0 + 2) * 256 + j] * ev;
            a2 += s_s[(h0 + 4) * 256 + j] * ev;
            a3 += s_s[(h0 + 6) * 256 + j] * ev;
        }
        g_s[(h0    ) * 128 + k] = a0;
        g_s[(h0 + 2) * 128 + k] = a1;
        g_s[(h0 + 4) * 128 + k] = a2;
        g_s[(h0 + 6) * 128 + k] = a3;
    }
    __syncthreads();
    {   // out[c] = sum_j att*vn + sum_k g*Wv + bv
        int c = tid & 127, half = tid >> 7;
        int h = c >> 4;
        float a = 0.f;
        for (int j = half * 128; j < half * 128 + 128; ++j)
            a += s_s[h * 256 + j] * vn[((long)(b * NN + j)) * 128 + c];
        for (int k = half * 64; k < half * 64 + 64; ++k)
            a += g_s[h * 128 + k] * b2f(Wv[k * 128 + c]);
        part[tid] = a;
    }
    __syncthreads();
    if (tid < 128)
        attn_o[((long)(b * NN + i)) * 128 + tid] = part[tid] + part[128 + tid] + bvp[tid];
}

// ---------------- K4: node path (Wo proj + LN1 + FFN + LN2) ----------------
__launch_bounds__(256)
__global__ void node_kernel(const float* __restrict__ attn_o, float* __restrict__ nf,
                            const float* __restrict__ Wo, const float* __restrict__ bo,
                            const float* __restrict__ Wn1, const float* __restrict__ bn1,
                            const float* __restrict__ Wn2, const float* __restrict__ bn2,
                            const float* __restrict__ g1, const float* __restrict__ b1,
                            const float* __restrict__ g2, const float* __restrict__ b2) {
    __shared__ float ao[128], nr[128], n1[128], hb[512];
    __shared__ float red[8];
    int tid = threadIdx.x;
    int wid = tid >> 6, lane = tid & 63;
    long base = (long)blockIdx.x * 128;
    if (tid < 128) { ao[tid] = attn_o[base + tid]; nr[tid] = nf[base + tid]; }
    __syncthreads();
    float x = 0.f;
    if (tid < 128) {
        float a = bo[tid];
        #pragma unroll 8
        for (int k = 0; k < 128; ++k) a += ao[k] * Wo[k * 128 + tid];
        x = nr[tid] + a;
    }
    float s = (tid < 128) ? x : 0.f, q = (tid < 128) ? x * x : 0.f;
    #pragma unroll
    for (int mk = 1; mk <= 32; mk <<= 1) { s += __shfl_xor(s, mk); q += __shfl_xor(q, mk); }
    if (lane == 0) { red[wid * 2] = s; red[wid * 2 + 1] = q; }
    __syncthreads();
    float sum = red[0] + red[2] + red[4] + red[6];
    float sq  = red[1] + red[3] + red[5] + red[7];
    float mean = sum * (1.f / 128.f);
    float var = sq * (1.f / 128.f) - mean * mean;
    float rs = rsqrtf(var + 1e-5f);
    __syncthreads();
    if (tid < 128) n1[tid] = (x - mean) * rs * g1[tid] + b1[tid];
    __syncthreads();
    for (int c = tid; c < 512; c += 256) {
        float a = bn1[c];
        #pragma unroll 8
        for (int k = 0; k < 128; ++k) a += n1[k] * Wn1[k * 512 + c];
        hb[c] = a > 0.f ? a : 0.f;
    }
    __syncthreads();
    float y = 0.f;
    if (tid < 128) {
        float a = bn2[tid];
        #pragma unroll 8
        for (int k = 0; k < 512; ++k) a += hb[k] * Wn2[k * 128 + tid];
        y = n1[tid] + a;
    }
    float s2 = (tid < 128) ? y : 0.f, q2 = (tid < 128) ? y * y : 0.f;
    #pragma unroll
    for (int mk = 1; mk <= 32; mk <<= 1) { s2 += __shfl_xor(s2, mk); q2 += __shfl_xor(q2, mk); }
    if (lane == 0) { red[wid * 2] = s2; red[wid * 2 + 1] = q2; }
    __syncthreads();
    sum = red[0] + red[2] + red[4] + red[6];
    sq  = red[1] + red[3] + red[5] + red[7];
    mean = sum * (1.f / 128.f);
    var = sq * (1.f / 128.f) - mean * mean;
    rs = rsqrtf(var + 1e-5f);
    if (tid < 128) {
        float o = (y - mean) * rs * g2[tid] + b2[tid];
        nf[base + tid] = o;
    }
}

// ---------------- fused edge-MLP: e_dst = LN(e_res + relu(A@W1 + pre)@W2 + b2) ----------------
// GEMM1 computed transposed (acc rows = hidden cols) so H lands in LDS via packed b64 writes.
// N=512 hidden processed in 4 quarters of 128; GEMM2 accumulates across quarters.
__launch_bounds__(512, 4)
__global__ void fused_mlp_kernel(const u16* __restrict__ W1T, const float* __restrict__ b1v,
                                 const u16* __restrict__ W2T, const float* __restrict__ b2v,
                                 const u16* __restrict__ ein, const u16* __restrict__ Aplain,
                                 const u16* __restrict__ e_res,
                                 const float* __restrict__ preS, const float* __restrict__ preT,
                                 const float* __restrict__ lng, const float* __restrict__ lnb,
                                 u16* __restrict__ e_dst, int K1, int cat_mode) {
    __shared__ char smem[65536];
    u16* As  = (u16*)smem;              // 16KB: A tile 128r x 64k (XOR-swizzled source)
    u16* BsW = (u16*)(smem + 16384);    // 16KB: weight tile 128n x 64k (GEMM1 & GEMM2)
    u16* Hs  = (u16*)(smem + 32768);    // 32KB: H tile 128r x 128n bf16, chunk-swizzled

    int tid = threadIdx.x;
    int wid = tid >> 6, lane = tid & 63;
    long row0 = (long)blockIdx.x * 128;
    int b = (int)(row0 >> 16);
    int rem0 = (int)(row0 & 65535);
    int i_ = rem0 >> 8, j0 = rem0 & 255;
    int wn = wid >> 2, wrr = wid & 3;    // GEMM1: wave = 64n x 32r
    int wr2 = wid >> 2, wc2 = wid & 3;   // GEMM2: wave = 64r x 32c
    int KT1 = K1 >> 6;

    f32x4 z = {0.f, 0.f, 0.f, 0.f};
    f32x4 acc2[4][2];
    #pragma unroll
    for (int m = 0; m < 4; ++m) { acc2[m][0] = z; acc2[m][1] = z; }

    for (int q = 0; q < 4; ++q) {
        int nq0 = q << 7;
        f32x4 acc1[4][2];
        #pragma unroll
        for (int m = 0; m < 4; ++m) { acc1[m][0] = z; acc1[m][1] = z; }

        // ---- GEMM1 quarter: H^T[128n][128r] over K1 ----
        for (int kt = 0; kt < KT1; ++kt) {
            int k0 = kt << 6;
            #pragma unroll
            for (int p = 0; p < 2; ++p) {
                int r = p * 64 + (tid >> 3);
                int ch = tid & 7;
                const u16* src;
                if (cat_mode) {
                    int seg = k0 >> 7;
                    int off = (k0 & 127) + ((ch ^ (r & 7)) << 3);
                    long ridx = seg == 0 ? (long)(b * NN + i_) * NN + (j0 + r)
                                         : (long)(b * NN + (j0 + r)) * NN + i_;
                    src = ein + ridx * DD + off;
                } else {
                    src = Aplain + (row0 + r) * K1 + k0 + ((ch ^ (r & 7)) << 3);
                }
                glds16(src, (char*)As + (p << 13) + (wid << 10));
                int n = p * 64 + (tid >> 3);
                const u16* wsrc = W1T + (long)(nq0 + n) * K1 + k0 + ((ch ^ (n & 7)) << 3);
                glds16(wsrc, (char*)BsW + (p << 13) + (wid << 10));
            }
            __syncthreads();
            #pragma unroll
            for (int ks = 0; ks < 2; ++ks) {
                bf16x8 af[4], bfr[2];
                #pragma unroll
                for (int mn = 0; mn < 4; ++mn) {
                    int n = wn * 64 + mn * 16 + (lane & 15);
                    int ch = (ks * 4 + (lane >> 4)) ^ (n & 7);
                    af[mn] = *reinterpret_cast<const bf16x8*>(&BsW[n * 64 + ch * 8]);
                }
                #pragma unroll
                for (int mr = 0; mr < 2; ++mr) {
                    int r = wrr * 32 + mr * 16 + (lane & 15);
                    int ch = (ks * 4 + (lane >> 4)) ^ (r & 7);
                    bfr[mr] = *reinterpret_cast<const bf16x8*>(&As[r * 64 + ch * 8]);
                }
                #pragma unroll
                for (int mn = 0; mn < 4; ++mn)
                    #pragma unroll
                    for (int mr = 0; mr < 2; ++mr)
                        acc1[mn][mr] = __builtin_amdgcn_mfma_f32_16x16x32_bf16(af[mn], bfr[mr], acc1[mn][mr], 0, 0, 0);
            }
            __syncthreads();
        }

        // ---- epilogue1: relu(acc1 + b1 [+preT+preS]) -> Hs (packed b64, swizzled) ----
        #pragma unroll
        for (int mn = 0; mn < 4; ++mn) {
            #pragma unroll
            for (int mr = 0; mr < 2; ++mr) {
                int nl0 = wn * 64 + mn * 16 + ((lane >> 4) << 2);  // local n, 4 consecutive
                int n0g = nq0 + nl0;
                int r = wrr * 32 + mr * 16 + (lane & 15);
                float4 bb = *reinterpret_cast<const float4*>(&b1v[n0g]);
                if (cat_mode) {
                    float4 pt = *reinterpret_cast<const float4*>(&preT[(long)(b * NN + i_) * 512 + n0g]);
                    float4 ps = *reinterpret_cast<const float4*>(&preS[(long)(b * NN + j0 + r) * 512 + n0g]);
                    bb.x += pt.x + ps.x; bb.y += pt.y + ps.y;
                    bb.z += pt.z + ps.z; bb.w += pt.w + ps.w;
                }
                float v0 = acc1[mn][mr][0] + bb.x; v0 = v0 > 0.f ? v0 : 0.f;
                float v1 = acc1[mn][mr][1] + bb.y; v1 = v1 > 0.f ? v1 : 0.f;
                float v2 = acc1[mn][mr][2] + bb.z; v2 = v2 > 0.f ? v2 : 0.f;
                float v3 = acc1[mn][mr][3] + bb.w; v3 = v3 > 0.f ? v3 : 0.f;
                uint2 pk;
                pk.x = (unsigned)f2b(v0) | ((unsigned)f2b(v1) << 16);
                pk.y = (unsigned)f2b(v2) | ((unsigned)f2b(v3) << 16);
                int c8 = nl0 >> 3;
                int cs = (c8 & 8) | ((c8 ^ r) & 7);
                *reinterpret_cast<uint2*>((char*)Hs + r * 256 + cs * 16 + (nl0 & 7) * 2) = pk;
            }
        }
        __syncthreads();

        // ---- GEMM2 partial: acc2 += H_q @ W2[:, nq0..nq0+127] ----
        #pragma unroll
        for (int kt2 = 0; kt2 < 2; ++kt2) {
            int k0g = nq0 + kt2 * 64;
            #pragma unroll
            for (int p = 0; p < 2; ++p) {
                int n = p * 64 + (tid >> 3);
                int ch = tid & 7;
                const u16* wsrc = W2T + (long)n * 512 + k0g + ((ch ^ (n & 7)) << 3);
                glds16(wsrc, (char*)BsW + (p << 13) + (wid << 10));
            }
            __syncthreads();
            #pragma unroll
            for (int ks = 0; ks < 2; ++ks) {
                bf16x8 af2[4], bf2[2];
                #pragma unroll
                for (int m = 0; m < 4; ++m) {
                    int r = wr2 * 64 + m * 16 + (lane & 15);
                    int lk = kt2 * 64 + ks * 32 + ((lane >> 4) << 3);
                    int c8 = lk >> 3;
                    int cs = (c8 & 8) | ((c8 ^ r) & 7);
                    af2[m] = *reinterpret_cast<const bf16x8*>((char*)Hs + r * 256 + cs * 16);
                }
                #pragma unroll
                for (int n = 0; n < 2; ++n) {
                    int c = wc2 * 32 + n * 16 + (lane & 15);
                    int ch = (ks * 4 + (lane >> 4)) ^ (c & 7);
                    bf2[n] = *reinterpret_cast<const bf16x8*>(&BsW[c * 64 + ch * 8]);
                }
                #pragma unroll
                for (int m = 0; m < 4; ++m)
                    #pragma unroll
                    for (int n = 0; n < 2; ++n)
                        acc2[m][n] = __builtin_amdgcn_mfma_f32_16x16x32_bf16(af2[m], bf2[n], acc2[m][n], 0, 0, 0);
            }
            __syncthreads();
        }
    }

    // ---- LN epilogue ----
    float* psum = (float*)smem;           // 2KB (reuse As region)
    float* psq  = (float*)(smem + 2048);  // 2KB
    #pragma unroll
    for (int m = 0; m < 4; ++m) {
        float sv[4], qv[4];
        #pragma unroll
        for (int t = 0; t < 4; ++t) { sv[t] = 0.f; qv[t] = 0.f; }
        #pragma unroll
        for (int n = 0; n < 2; ++n) {
            int col = wc2 * 32 + n * 16 + (lane & 15);
            float bb = b2v[col];
            #pragma unroll
            for (int t = 0; t < 4; ++t) {
                long row = wr2 * 64 + m * 16 + ((lane >> 4) << 2) + t;
                float xv = acc2[m][n][t] + bb + b2f(e_res[(row0 + row) * 128 + col]);
                acc2[m][n][t] = xv;
                sv[t] += xv;
                qv[t] += xv * xv;
            }
        }
        #pragma unroll
        for (int mk = 1; mk <= 8; mk <<= 1)
            #pragma unroll
            for (int t = 0; t < 4; ++t) { sv[t] += __shfl_xor(sv[t], mk); qv[t] += __shfl_xor(qv[t], mk); }
        if ((lane & 15) == 0) {
            #pragma unroll
            for (int t = 0; t < 4; ++t) {
                int row = wr2 * 64 + m * 16 + ((lane >> 4) << 2) + t;
                psum[row * 4 + wc2] = sv[t];
                psq[row * 4 + wc2] = qv[t];
            }
        }
    }
    __syncthreads();
    #pragma unroll
    for (int m = 0; m < 4; ++m) {
        #pragma unroll
        for (int t = 0; t < 4; ++t) {
            int row = wr2 * 64 + m * 16 + ((lane >> 4) << 2) + t;
            float sum = psum[row * 4] + psum[row * 4 + 1] + psum[row * 4 + 2] + psum[row * 4 + 3];
            float sq  = psq[row * 4] + psq[row * 4 + 1] + psq[row * 4 + 2] + psq[row * 4 + 3];
            float mean = sum * (1.f / 128.f);
            float var = sq * (1.f / 128.f) - mean * mean;
            float rs = rsqrtf(var + 1e-5f);
            #pragma unroll
            for (int n = 0; n < 2; ++n) {
                int col = wc2 * 32 + n * 16 + (lane & 15);
                float o = (acc2[m][n][t] - mean) * rs * lng[col] + lnb[col];
                e_dst[(row0 + row) * 128 + col] = f2b(o);
            }
        }
    }
}

extern "C" void kernel_launch(void* const* d_in, const int* in_sizes, int n_in,
                              void* d_out, int out_size, void* d_ws, size_t ws_size,
                              hipStream_t stream) {
    (void)in_sizes; (void)n_in; (void)out_size; (void)ws_size;
    const float* node   = (const float*)d_in[0];
    const float* edge   = (const float*)d_in[1];
    const float* Wqkv_n = (const float*)d_in[2];
    const float* bqkv_n = (const float*)d_in[3];
    const float* Wqkv_e = (const float*)d_in[4];
    const float* bqkv_e = (const float*)d_in[5];
    const float* Wo     = (const float*)d_in[6];
    const float* bo     = (const float*)d_in[7];
    const float* Wn1    = (const float*)d_in[8];
    const float* bn1    = (const float*)d_in[9];
    const float* Wn2    = (const float*)d_in[10];
    const float* bn2    = (const float*)d_in[11];
    const float* ln1n_g = (const float*)d_in[12];
    const float* ln1n_b = (const float*)d_in[13];
    const float* ln2n_g = (const float*)d_in[14];
    const float* ln2n_b = (const float*)d_in[15];
    const float* We1a   = (const float*)d_in[16];
    const float* be1a   = (const float*)d_in[17];
    const float* We1b   = (const float*)d_in[18];
    const float* be1b   = (const float*)d_in[19];
    const float* We2a   = (const float*)d_in[20];
    const float* be2a   = (const float*)d_in[21];
    const float* We2b   = (const float*)d_in[22];
    const float* be2b   = (const float*)d_in[23];
    const float* ln1e_g = (const float*)d_in[24];
    const float* ln1e_b = (const float*)d_in[25];
    const float* ln2e_g = (const float*)d_in[26];
    const float* ln2e_b = (const float*)d_in[27];

    size_t off = 0;
    char* wsb = (char*)d_ws;
    auto alloc = [&](size_t bytes) -> void* {
        void* p = wsb + off;
        off = (off + bytes + 255) & ~(size_t)255;
        return p;
    };
    u16* eb0      = (u16*)alloc((size_t)RNN * 128 * 2);
    u16* eb1      = (u16*)alloc((size_t)RNN * 128 * 2);
    float* scoresp= (float*)alloc((size_t)2097152 * 4);
    float* qn     = (float*)alloc(131072 * 4);
    float* vn     = (float*)alloc(131072 * 4);
    float* attn_o = (float*)alloc(131072 * 4);
    float* nf     = (float*)alloc(131072 * 4);
    float* preS   = (float*)alloc((size_t)1024 * 512 * 4);
    float* preT   = (float*)alloc((size_t)1024 * 512 * 4);
    u16* wqT      = (u16*)alloc(3 * 16384 * 2);
    u16* wv       = (u16*)alloc(3 * 16384 * 2);
    float* bqp    = (float*)alloc(3 * 128 * 4);
    float* bvp    = (float*)alloc(3 * 128 * 4);
    u16* we1aT    = (u16*)alloc(3 * 131072ull * 2);
    u16* we1bT    = (u16*)alloc(3 * 65536 * 2);
    u16* we2aT    = (u16*)alloc(3 * 65536 * 2);
    u16* we2bT    = (u16*)alloc(3 * 65536 * 2);

    {
        dim3 g(1024, 6, 3);
        prep_weights<<<g, 256, 0, stream>>>(Wqkv_e, bqkv_e, We1a, We1b, We2a, We2b,
                                            wqT, wv, bqp, bvp, we1aT, we1bT, we2aT, we2bT);
    }
    init_e<<<2048, 256, 0, stream>>>((const float4*)edge, (ushort4*)eb0);
    init_n<<<512, 256, 0, stream>>>(node, nf);

    for (int l = 0; l < 3; ++l) {
        u16* ein  = (l & 1) ? eb1 : eb0;
        u16* eout = (l & 1) ? eb0 : eb1;
        qkvn_kernel<<<1024, 256, 0, stream>>>(nf, Wqkv_n + l * 49152, bqkv_n + l * 384, qn, vn);
        scores_kernel<<<2048, 256, 0, stream>>>(ein, wqT + l * 16384, bqp + l * 128, qn, scoresp);
        attn_pv_kernel<<<1024, 256, 0, stream>>>(scoresp, ein, vn, wv + l * 16384, bvp + l * 128, attn_o);
        node_kernel<<<1024, 256, 0, stream>>>(attn_o, nf,
                                              Wo + l * 16384, bo + l * 128,
                                              Wn1 + l * 65536, bn1 + l * 512,
                                              Wn2 + l * 65536, bn2 + l * 128,
                                              ln1n_g + l * 128, ln1n_b + l * 128,
                                              ln2n_g + l * 128, ln2n_b + l * 128);
        pre_node_kernel<<<1024, 512, 0, stream>>>(nf, We1a + (size_t)l * 262144, preS, preT);
        // e1 update: eout = LN(ein + relu(cat@We1a + pre)@We1b + b)
        fused_mlp_kernel<<<2048, 512, 0, stream>>>(we1aT + l * 131072, be1a + l * 512,
                                                   we1bT + l * 65536, be1b + l * 128,
                                                   ein, nullptr, ein, preS, preT,
                                                   ln1e_g + l * 128, ln1e_b + l * 128,
                                                   eout, 256, 1);
        // e2 update (in-place): eout = LN(eout + relu(eout@We2a + b)@We2b + b)
        fused_mlp_kernel<<<2048, 512, 0, stream>>>(we2aT + l * 65536, be2a + l * 512,
                                                   we2bT + l * 65536, be2b + l * 128,
                                                   nullptr, eout, eout, nullptr, nullptr,
                                                   ln2e_g + l * 128, ln2e_b + l * 128,
                                                   eout, 128, 0);
    }
    hipMemcpyAsync(d_out, nf, 131072 * sizeof(float), hipMemcpyDeviceToDevice, stream);
}

// Round 4
// 1531.202 us; speedup vs baseline: 1.5254x; 1.4179x over previous
//
#include <hip/hip_runtime.h>

typedef unsigned short u16;
typedef __bf16 bf16x8 __attribute__((ext_vector_type(8)));
typedef float f32x4 __attribute__((ext_vector_type(4)));

#define NB 4
#define NN 256
#define DD 128
#define RNN 262144   // NB*NN*NN

__device__ __forceinline__ u16 f2b(float f) {
    unsigned u = __builtin_bit_cast(unsigned, f);
    unsigned rb = ((u >> 16) & 1u) + 0x7FFFu;
    return (u16)((u + rb) >> 16);
}
__device__ __forceinline__ float b2f(u16 u) {
    return __builtin_bit_cast(float, ((unsigned)u) << 16);
}

__device__ __forceinline__ void glds16(const void* g, void* l) {
    __builtin_amdgcn_global_load_lds((const __attribute__((address_space(1))) void*)g,
                                     (__attribute__((address_space(3))) void*)l, 16, 0, 0);
}

// ---------------- weight prep: bf16 convert + transpose to [N][K] ----------------
__global__ void prep_weights(const float* __restrict__ Wqkv_e, const float* __restrict__ bqkv_e,
                             const float* __restrict__ We1a, const float* __restrict__ We1b,
                             const float* __restrict__ We2a, const float* __restrict__ We2b,
                             u16* wqT, u16* wv, float* bqp, float* bvp,
                             u16* we1aT, u16* we1bT, u16* we2aT, u16* we2bT) {
    int l = blockIdx.z, sec = blockIdx.y;
    int idx = blockIdx.x * 256 + threadIdx.x;
    if (sec == 0) {            // WqT[l][n*128+k] = Wqkv_e[l][k][qcol(n)]
        if (idx < 16384) {
            int n = idx >> 7, k = idx & 127;
            int col = (n >> 4) * 48 + (n & 15);
            wqT[l * 16384 + n * 128 + k] = f2b(Wqkv_e[l * 49152 + k * 384 + col]);
        }
    } else if (sec == 1) {     // Wv plain [k][c]
        if (idx < 16384) {
            int k = idx >> 7, c = idx & 127;
            int col = (c >> 4) * 48 + 32 + (c & 15);
            wv[l * 16384 + k * 128 + c] = f2b(Wqkv_e[l * 49152 + k * 384 + col]);
        }
        if (idx < 128) {
            bqp[l * 128 + idx] = bqkv_e[l * 384 + (idx >> 4) * 48 + (idx & 15)];
            bvp[l * 128 + idx] = bqkv_e[l * 384 + (idx >> 4) * 48 + 32 + (idx & 15)];
        }
    } else if (sec == 2) {     // We1aT [512 n][256 k] — only e/eT segments (K rows 0..255)
        if (idx < 131072) {
            int n = idx >> 8, k = idx & 255;
            we1aT[l * 131072 + n * 256 + k] = f2b(We1a[l * 262144 + k * 512 + n]);
        }
    } else if (sec == 3) {     // We1bT [128][512]
        if (idx < 65536) {
            int n = idx >> 9, k = idx & 511;
            we1bT[l * 65536 + n * 512 + k] = f2b(We1b[l * 65536 + k * 128 + n]);
        }
    } else if (sec == 4) {     // We2aT [512][128]
        if (idx < 65536) {
            int n = idx >> 7, k = idx & 127;
            we2aT[l * 65536 + n * 128 + k] = f2b(We2a[l * 65536 + k * 512 + n]);
        }
    } else {                   // We2bT [128][512]
        if (idx < 65536) {
            int n = idx >> 9, k = idx & 511;
            we2bT[l * 65536 + n * 512 + k] = f2b(We2b[l * 65536 + k * 128 + n]);
        }
    }
}

__global__ void init_e(const float4* __restrict__ src, ushort4* __restrict__ dst) {
    const long n4 = 8388608;  // 33.5M elems /4
    for (long i = (long)blockIdx.x * blockDim.x + threadIdx.x; i < n4; i += (long)gridDim.x * blockDim.x) {
        float4 v = src[i];
        ushort4 o;
        o.x = f2b(v.x); o.y = f2b(v.y); o.z = f2b(v.z); o.w = f2b(v.w);
        dst[i] = o;
    }
}

__global__ void init_n(const float* __restrict__ node, float* __restrict__ nf) {
    int i = blockIdx.x * 256 + threadIdx.x;
    if (i < 131072) nf[i] = node[i];
}

// ---------------- pre_node: preS[b,j,c] = n[b,j]·We1a_seg2[:,c]; preT[b,i,c] = n[b,i]·We1a_seg3[:,c]
__launch_bounds__(512)
__global__ void pre_node_kernel(const float* __restrict__ nf, const float* __restrict__ We1a,
                                float* __restrict__ preS, float* __restrict__ preT) {
    __shared__ float nr[128];
    int tid = threadIdx.x;
    int row = blockIdx.x;   // b*256 + n
    if (tid < 128) nr[tid] = nf[(long)row * 128 + tid];
    __syncthreads();
    int c = tid;            // 0..511
    float s = 0.f, t = 0.f;
    const float* Ws = We1a + (long)256 * 512 + c;   // seg2 rows 256..383
    const float* Wt = We1a + (long)384 * 512 + c;   // seg3 rows 384..511
    #pragma unroll 8
    for (int k = 0; k < 128; ++k) {
        float nv = nr[k];
        s += nv * Ws[k * 512];
        t += nv * Wt[k * 512];
    }
    preS[(long)row * 512 + c] = s;
    preT[(long)row * 512 + c] = t;
}

// ---------------- K1: qn/vn = n @ Wqkv_n (packed head-major cols) ----------------
__global__ void qkvn_kernel(const float* __restrict__ nf, const float* __restrict__ W,
                            const float* __restrict__ bias, float* __restrict__ qn, float* __restrict__ vn) {
    __shared__ float nr[128];
    int tid = threadIdx.x;
    int row = blockIdx.x;                // b*256+i
    if (tid < 128) nr[tid] = nf[(long)row * 128 + tid];
    __syncthreads();
    int c = tid & 127;
    bool isq = tid < 128;
    int col = (c >> 4) * 48 + (c & 15) + (isq ? 0 : 32);
    float a = bias[col];
    #pragma unroll 8
    for (int k = 0; k < 128; ++k) a += nr[k] * W[k * 384 + col];
    if (isq) qn[(long)row * 128 + c] = a;
    else     vn[(long)row * 128 + c] = a;
}

// ---------------- K2: scores[b,h,i,j] = scale*||qn+ e@Wq + bq||^2 ----------------
__launch_bounds__(256, 2)
__global__ void scores_kernel(const u16* __restrict__ ein, const u16* __restrict__ WqT,
                              const float* __restrict__ bqp, const float* __restrict__ qn,
                              float* __restrict__ scoresp) {
    __shared__ u16 As[128 * 64];
    __shared__ u16 Bs[128 * 64];
    int tid = threadIdx.x;
    int wid = tid >> 6, lane = tid & 63;
    int bid = blockIdx.x;
    int jhalf = bid & 1, bi = bid >> 1;
    int b = bi >> 8, i = bi & 255;
    int wr = wid >> 1, wc = wid & 1;   // 2x2 waves, wave=64 rows x 64 cols

    f32x4 acc[4][4];
    f32x4 z = {0.f, 0.f, 0.f, 0.f};
    #pragma unroll
    for (int m = 0; m < 4; ++m)
        #pragma unroll
        for (int n = 0; n < 4; ++n) acc[m][n] = z;

    const long arow0 = ((long)(b * NN + i) * NN + jhalf * 128);
    for (int kt = 0; kt < 2; ++kt) {
        int k0 = kt << 6;
        #pragma unroll
        for (int p = 0; p < 4; ++p) {
            int r = p * 32 + (tid >> 3);
            int ch = tid & 7;
            const u16* src = ein + (arow0 + r) * 128 + k0 + ((ch ^ (r & 7)) << 3);
            glds16(src, (char*)As + (p << 12) + (wid << 10));
            int n = p * 32 + (tid >> 3);
            const u16* bsrc = WqT + (long)n * 128 + k0 + ((ch ^ (n & 7)) << 3);
            glds16(bsrc, (char*)Bs + (p << 12) + (wid << 10));
        }
        __syncthreads();
        #pragma unroll
        for (int ks = 0; ks < 2; ++ks) {
            bf16x8 af[4], bfr[4];
            #pragma unroll
            for (int m = 0; m < 4; ++m) {
                int r = wr * 64 + m * 16 + (lane & 15);
                int ch = (ks * 4 + (lane >> 4)) ^ (r & 7);
                af[m] = *reinterpret_cast<const bf16x8*>(&As[r * 64 + ch * 8]);
            }
            #pragma unroll
            for (int n = 0; n < 4; ++n) {
                int c = wc * 64 + n * 16 + (lane & 15);
                int ch = (ks * 4 + (lane >> 4)) ^ (c & 7);
                bfr[n] = *reinterpret_cast<const bf16x8*>(&Bs[c * 64 + ch * 8]);
            }
            #pragma unroll
            for (int m = 0; m < 4; ++m)
                #pragma unroll
                for (int n = 0; n < 4; ++n)
                    acc[m][n] = __builtin_amdgcn_mfma_f32_16x16x32_bf16(af[m], bfr[n], acc[m][n], 0, 0, 0);
        }
        __syncthreads();
    }
    const float* qnb = qn + (long)(b * NN + i) * 128;
    #pragma unroll
    for (int m = 0; m < 4; ++m) {
        #pragma unroll
        for (int n = 0; n < 4; ++n) {
            int col = wc * 64 + n * 16 + (lane & 15);
            float add = bqp[col] + qnb[col];
            float sv[4];
            #pragma unroll
            for (int t = 0; t < 4; ++t) { float qv = acc[m][n][t] + add; sv[t] = qv * qv; }
            #pragma unroll
            for (int mk = 1; mk <= 8; mk <<= 1)
                #pragma unroll
                for (int t = 0; t < 4; ++t) sv[t] += __shfl_xor(sv[t], mk);
            if ((lane & 15) == 0) {
                int head = wc * 4 + n;
                int jb = jhalf * 128 + wr * 64 + m * 16 + ((lane >> 4) << 2);
                long sbase = ((long)(b * 8 + head) * 256 + i) * 256 + jb;
                #pragma unroll
                for (int t = 0; t < 4; ++t) scoresp[sbase + t] = sv[t] * 0.25f;
            }
        }
    }
}

// ---------------- K3: softmax + factored PV ----------------
__launch_bounds__(256)
__global__ void attn_pv_kernel(const float* __restrict__ scoresp, const u16* __restrict__ ein,
                               const float* __restrict__ vn, const u16* __restrict__ Wv,
                               const float* __restrict__ bvp, float* __restrict__ attn_o) {
    __shared__ float s_s[8 * 256];
    __shared__ float g_s[8 * 128];
    __shared__ float part[256];
    int tid = threadIdx.x;
    int b = blockIdx.x >> 8, i = blockIdx.x & 255;
    for (int v = tid; v < 2048; v += 256) {
        int h = v >> 8, j = v & 255;
        s_s[v] = scoresp[((long)(b * 8 + h) * 256 + i) * 256 + j];
    }
    __syncthreads();
    {   // softmax: 8 groups of 32 lanes, one head each
        int h = tid >> 5, lg = tid & 31;
        float vals[8], mx = -1e30f;
        #pragma unroll
        for (int t = 0; t < 8; ++t) { vals[t] = s_s[h * 256 + lg + t * 32]; mx = fmaxf(mx, vals[t]); }
        #pragma unroll
        for (int mk = 16; mk; mk >>= 1) mx = fmaxf(mx, __shfl_xor(mx, mk));
        float sum = 0.f;
        #pragma unroll
        for (int t = 0; t < 8; ++t) { vals[t] = __expf(vals[t] - mx); sum += vals[t]; }
        #pragma unroll
        for (int mk = 16; mk; mk >>= 1) sum += __shfl_xor(sum, mk);
        float inv = 1.f / sum;
        #pragma unroll
        for (int t = 0; t < 8; ++t) s_s[h * 256 + lg + t * 32] = vals[t] * inv;
    }
    __syncthreads();
    {   // g[h][k] = sum_j att[h][j]*e[b,i,j,k]
        int k = tid & 127, h0 = tid >> 7;  // 0/1
        const u16* erow = ein + ((long)(b * NN + i) * NN) * 128 + k;
        float a0 = 0, a1 = 0, a2 = 0, a3 = 0;
        for (int j = 0; j < 256; ++j) {
            float ev = b2f(erow[(long)j * 128]);
            a0 += s_s[(h0    ) * 256 + j] * ev;
            a1 += s_s[(h0 + 2) * 256 + j] * ev;
            a2 += s_s[(h0 + 4) * 256 + j] * ev;
            a3 += s_s[(h0 + 6) * 256 + j] * ev;
        }
        g_s[(h0    ) * 128 + k] = a0;
        g_s[(h0 + 2) * 128 + k] = a1;
        g_s[(h0 + 4) * 128 + k] = a2;
        g_s[(h0 + 6) * 128 + k] = a3;
    }
    __syncthreads();
    {   // out[c] = sum_j att*vn + sum_k g*Wv + bv
        int c = tid & 127, half = tid >> 7;
        int h = c >> 4;
        float a = 0.f;
        for (int j = half * 128; j < half * 128 + 128; ++j)
            a += s_s[h * 256 + j] * vn[((long)(b * NN + j)) * 128 + c];
        for (int k = half * 64; k < half * 64 + 64; ++k)
            a += g_s[h * 128 + k] * b2f(Wv[k * 128 + c]);
        part[tid] = a;
    }
    __syncthreads();
    if (tid < 128)
        attn_o[((long)(b * NN + i)) * 128 + tid] = part[tid] + part[128 + tid] + bvp[tid];
}

// ---------------- K4: node path (Wo proj + LN1 + FFN + LN2) ----------------
__launch_bounds__(256)
__global__ void node_kernel(const float* __restrict__ attn_o, float* __restrict__ nf,
                            const float* __restrict__ Wo, const float* __restrict__ bo,
                            const float* __restrict__ Wn1, const float* __restrict__ bn1,
                            const float* __restrict__ Wn2, const float* __restrict__ bn2,
                            const float* __restrict__ g1, const float* __restrict__ b1,
                            const float* __restrict__ g2, const float* __restrict__ b2) {
    __shared__ float ao[128], nr[128], n1[128], hb[512];
    __shared__ float red[8];
    int tid = threadIdx.x;
    int wid = tid >> 6, lane = tid & 63;
    long base = (long)blockIdx.x * 128;
    if (tid < 128) { ao[tid] = attn_o[base + tid]; nr[tid] = nf[base + tid]; }
    __syncthreads();
    float x = 0.f;
    if (tid < 128) {
        float a = bo[tid];
        #pragma unroll 8
        for (int k = 0; k < 128; ++k) a += ao[k] * Wo[k * 128 + tid];
        x = nr[tid] + a;
    }
    float s = (tid < 128) ? x : 0.f, q = (tid < 128) ? x * x : 0.f;
    #pragma unroll
    for (int mk = 1; mk <= 32; mk <<= 1) { s += __shfl_xor(s, mk); q += __shfl_xor(q, mk); }
    if (lane == 0) { red[wid * 2] = s; red[wid * 2 + 1] = q; }
    __syncthreads();
    float sum = red[0] + red[2] + red[4] + red[6];
    float sq  = red[1] + red[3] + red[5] + red[7];
    float mean = sum * (1.f / 128.f);
    float var = sq * (1.f / 128.f) - mean * mean;
    float rs = rsqrtf(var + 1e-5f);
    __syncthreads();
    if (tid < 128) n1[tid] = (x - mean) * rs * g1[tid] + b1[tid];
    __syncthreads();
    for (int c = tid; c < 512; c += 256) {
        float a = bn1[c];
        #pragma unroll 8
        for (int k = 0; k < 128; ++k) a += n1[k] * Wn1[k * 512 + c];
        hb[c] = a > 0.f ? a : 0.f;
    }
    __syncthreads();
    float y = 0.f;
    if (tid < 128) {
        float a = bn2[tid];
        #pragma unroll 8
        for (int k = 0; k < 512; ++k) a += hb[k] * Wn2[k * 128 + tid];
        y = n1[tid] + a;
    }
    float s2 = (tid < 128) ? y : 0.f, q2 = (tid < 128) ? y * y : 0.f;
    #pragma unroll
    for (int mk = 1; mk <= 32; mk <<= 1) { s2 += __shfl_xor(s2, mk); q2 += __shfl_xor(q2, mk); }
    if (lane == 0) { red[wid * 2] = s2; red[wid * 2 + 1] = q2; }
    __syncthreads();
    sum = red[0] + red[2] + red[4] + red[6];
    sq  = red[1] + red[3] + red[5] + red[7];
    mean = sum * (1.f / 128.f);
    var = sq * (1.f / 128.f) - mean * mean;
    rs = rsqrtf(var + 1e-5f);
    if (tid < 128) {
        float o = (y - mean) * rs * g2[tid] + b2[tid];
        nf[base + tid] = o;
    }
}

// ---------------- fused edge-MLP v2: A LDS-resident, 64 rows/block, 256 threads ----------------
// e_dst = LN(e_res + relu(A@W1 + pre)@W2 + b2).  KT1 = K1/64 (4 for e1-cat, 2 for e2).
template<int KT1, int CAT>
__launch_bounds__(256, 2)
__global__ void fused_mlp2(const u16* __restrict__ W1T, const float* __restrict__ b1v,
                           const u16* __restrict__ W2T, const float* __restrict__ b2v,
                           const u16* __restrict__ ein, const u16* __restrict__ Aplain,
                           const u16* __restrict__ e_res,
                           const float* __restrict__ preS, const float* __restrict__ preT,
                           const float* __restrict__ lng, const float* __restrict__ lnb,
                           u16* __restrict__ e_dst) {
    __shared__ u16 A_lds[KT1 * 4096];   // [KT1][64r][64k] swizzled  (32KB / 16KB)
    __shared__ u16 Ws[8192];            // 16KB weight tile: [128][64k] swizzled
    __shared__ u16 Hs[8192];            // 16KB H tile: [64r][128n] chunk-swizzled

    const int K1 = KT1 * 64;
    int tid = threadIdx.x;
    int wid = tid >> 6, lane = tid & 63;
    long row0 = (long)blockIdx.x * 64;
    int b = (int)(row0 >> 16);
    int rem0 = (int)(row0 & 65535);
    int i_ = rem0 >> 8, j0 = rem0 & 255;
    // GEMM1: 2 waves n (wn) x 2 waves r (wrr); GEMM2: 2 waves r (wr2) x 2 waves c (wc2)
    int wn = wid >> 1, wrr = wid & 1;
    int wr2 = wid >> 1, wc2 = wid & 1;

    // ---- stage A once: [KT1][64][64] ----
    #pragma unroll
    for (int kt = 0; kt < KT1; ++kt) {
        #pragma unroll
        for (int p = 0; p < 2; ++p) {
            int r = p * 32 + (tid >> 3);
            int ch = tid & 7;
            const u16* src;
            if (CAT) {
                int seg = kt >> 1;
                int off = ((kt & 1) << 6) + ((ch ^ (r & 7)) << 3);
                long ridx = seg == 0 ? (long)(b * NN + i_) * NN + (j0 + r)
                                     : (long)(b * NN + (j0 + r)) * NN + i_;
                src = ein + ridx * DD + off;
            } else {
                src = Aplain + (row0 + r) * K1 + (kt << 6) + ((ch ^ (r & 7)) << 3);
            }
            glds16(src, (char*)A_lds + kt * 8192 + (p << 12) + (wid << 10));
        }
    }

    f32x4 z = {0.f, 0.f, 0.f, 0.f};
    f32x4 acc2[2][4];
    #pragma unroll
    for (int m = 0; m < 2; ++m)
        #pragma unroll
        for (int n = 0; n < 4; ++n) acc2[m][n] = z;

    for (int q = 0; q < 4; ++q) {
        int nq0 = q << 7;
        f32x4 acc1[4][2];
        #pragma unroll
        for (int mn = 0; mn < 4; ++mn) { acc1[mn][0] = z; acc1[mn][1] = z; }

        // ---- GEMM1: H^T[128n][64r] over K1, A from resident LDS ----
        #pragma unroll
        for (int kt = 0; kt < KT1; ++kt) {
            #pragma unroll
            for (int pp = 0; pp < 4; ++pp) {           // stage W1 tile 128n x 64k
                int n = pp * 32 + (tid >> 3);
                int ch = tid & 7;
                const u16* src = W1T + (long)(nq0 + n) * K1 + (kt << 6) + ((ch ^ (n & 7)) << 3);
                glds16(src, (char*)Ws + (pp << 12) + (wid << 10));
            }
            __syncthreads();
            #pragma unroll
            for (int ks = 0; ks < 2; ++ks) {
                bf16x8 af[4], bfr[2];
                #pragma unroll
                for (int mn = 0; mn < 4; ++mn) {
                    int n = wn * 64 + mn * 16 + (lane & 15);
                    int ch = (ks * 4 + (lane >> 4)) ^ (n & 7);
                    af[mn] = *reinterpret_cast<const bf16x8*>(&Ws[n * 64 + ch * 8]);
                }
                #pragma unroll
                for (int mr = 0; mr < 2; ++mr) {
                    int r = wrr * 32 + mr * 16 + (lane & 15);
                    int ch = (ks * 4 + (lane >> 4)) ^ (r & 7);
                    bfr[mr] = *reinterpret_cast<const bf16x8*>(&A_lds[kt * 4096 + r * 64 + ch * 8]);
                }
                #pragma unroll
                for (int mn = 0; mn < 4; ++mn)
                    #pragma unroll
                    for (int mr = 0; mr < 2; ++mr)
                        acc1[mn][mr] = __builtin_amdgcn_mfma_f32_16x16x32_bf16(af[mn], bfr[mr], acc1[mn][mr], 0, 0, 0);
            }
            __syncthreads();
        }

        // after last quarter's GEMM1, A region is free: prefetch e_res into it
        if (q == 3) {
            #pragma unroll
            for (int p = 0; p < 4; ++p) {
                int rr = p * 16 + (tid >> 4);
                const u16* src = e_res + (row0 + rr) * DD + ((tid & 15) << 3);
                glds16(src, (char*)A_lds + (p << 12) + (wid << 10));
            }
        }

        // ---- epilogue1: relu(acc1 + b1 [+preT+preS]) -> Hs (packed b64, swizzled) ----
        #pragma unroll
        for (int mn = 0; mn < 4; ++mn) {
            #pragma unroll
            for (int mr = 0; mr < 2; ++mr) {
                int nl0 = wn * 64 + mn * 16 + ((lane >> 4) << 2);
                int n0g = nq0 + nl0;
                int r = wrr * 32 + mr * 16 + (lane & 15);
                float4 bb = *reinterpret_cast<const float4*>(&b1v[n0g]);
                if (CAT) {
                    float4 pt = *reinterpret_cast<const float4*>(&preT[(long)(b * NN + i_) * 512 + n0g]);
                    float4 ps = *reinterpret_cast<const float4*>(&preS[(long)(b * NN + j0 + r) * 512 + n0g]);
                    bb.x += pt.x + ps.x; bb.y += pt.y + ps.y;
                    bb.z += pt.z + ps.z; bb.w += pt.w + ps.w;
                }
                float v0 = acc1[mn][mr][0] + bb.x; v0 = v0 > 0.f ? v0 : 0.f;
                float v1 = acc1[mn][mr][1] + bb.y; v1 = v1 > 0.f ? v1 : 0.f;
                float v2 = acc1[mn][mr][2] + bb.z; v2 = v2 > 0.f ? v2 : 0.f;
                float v3 = acc1[mn][mr][3] + bb.w; v3 = v3 > 0.f ? v3 : 0.f;
                uint2 pk;
                pk.x = (unsigned)f2b(v0) | ((unsigned)f2b(v1) << 16);
                pk.y = (unsigned)f2b(v2) | ((unsigned)f2b(v3) << 16);
                int c8 = nl0 >> 3;
                int cs = (c8 & 8) | ((c8 ^ r) & 7);
                *reinterpret_cast<uint2*>((char*)Hs + r * 256 + cs * 16 + (nl0 & 7) * 2) = pk;
            }
        }

        // ---- GEMM2 partial: acc2 += H_q @ W2[:, quarter k-slice] ----
        #pragma unroll
        for (int kt2 = 0; kt2 < 2; ++kt2) {
            #pragma unroll
            for (int pp = 0; pp < 4; ++pp) {           // stage W2 tile 128c x 64k
                int c = pp * 32 + (tid >> 3);
                int ch = tid & 7;
                const u16* src = W2T + (long)c * 512 + nq0 + (kt2 << 6) + ((ch ^ (c & 7)) << 3);
                glds16(src, (char*)Ws + (pp << 12) + (wid << 10));
            }
            __syncthreads();   // covers Hs writes (kt2=0) + W2 staging
            #pragma unroll
            for (int ks = 0; ks < 2; ++ks) {
                bf16x8 af2[2], bf2[4];
                #pragma unroll
                for (int m = 0; m < 2; ++m) {
                    int r = wr2 * 32 + m * 16 + (lane & 15);
                    int lk = kt2 * 64 + ks * 32 + ((lane >> 4) << 3);
                    int c8 = lk >> 3;
                    int cs = (c8 & 8) | ((c8 ^ r) & 7);
                    af2[m] = *reinterpret_cast<const bf16x8*>((char*)Hs + r * 256 + cs * 16);
                }
                #pragma unroll
                for (int n = 0; n < 4; ++n) {
                    int c = wc2 * 64 + n * 16 + (lane & 15);
                    int ch = (ks * 4 + (lane >> 4)) ^ (c & 7);
                    bf2[n] = *reinterpret_cast<const bf16x8*>(&Ws[c * 64 + ch * 8]);
                }
                #pragma unroll
                for (int m = 0; m < 2; ++m)
                    #pragma unroll
                    for (int n = 0; n < 4; ++n)
                        acc2[m][n] = __builtin_amdgcn_mfma_f32_16x16x32_bf16(af2[m], bf2[n], acc2[m][n], 0, 0, 0);
            }
            __syncthreads();
        }
    }

    // ---- LN epilogue: x = acc2 + b2 + e_res(LDS); per-row mean/var; write via LDS repack ----
    float* psum = (float*)Hs;            // 64*2 floats
    float* psq  = psum + 128;
    u16* eres_lds = A_lds;               // [64][128] linear (staged during q==3)
    #pragma unroll
    for (int m = 0; m < 2; ++m) {
        float sv[4], qv[4];
        #pragma unroll
        for (int t = 0; t < 4; ++t) { sv[t] = 0.f; qv[t] = 0.f; }
        #pragma unroll
        for (int n = 0; n < 4; ++n) {
            int col = wc2 * 64 + n * 16 + (lane & 15);
            float bb = b2v[col];
            #pragma unroll
            for (int t = 0; t < 4; ++t) {
                int row = wr2 * 32 + m * 16 + ((lane >> 4) << 2) + t;
                float xv = acc2[m][n][t] + bb + b2f(eres_lds[row * 128 + col]);
                acc2[m][n][t] = xv;
                sv[t] += xv;
                qv[t] += xv * xv;
            }
        }
        #pragma unroll
        for (int mk = 1; mk <= 8; mk <<= 1)
            #pragma unroll
            for (int t = 0; t < 4; ++t) { sv[t] += __shfl_xor(sv[t], mk); qv[t] += __shfl_xor(qv[t], mk); }
        if ((lane & 15) == 0) {
            #pragma unroll
            for (int t = 0; t < 4; ++t) {
                int row = wr2 * 32 + m * 16 + ((lane >> 4) << 2) + t;
                psum[row * 2 + wc2] = sv[t];
                psq[row * 2 + wc2] = qv[t];
            }
        }
    }
    __syncthreads();
    #pragma unroll
    for (int m = 0; m < 2; ++m) {
        #pragma unroll
        for (int t = 0; t < 4; ++t) {
            int row = wr2 * 32 + m * 16 + ((lane >> 4) << 2) + t;
            float sum = psum[row * 2] + psum[row * 2 + 1];
            float sq  = psq[row * 2] + psq[row * 2 + 1];
            float mean = sum * (1.f / 128.f);
            float var = sq * (1.f / 128.f) - mean * mean;
            float rs = rsqrtf(var + 1e-5f);
            #pragma unroll
            for (int n = 0; n < 4; ++n) {
                int col = wc2 * 64 + n * 16 + (lane & 15);
                float o = (acc2[m][n][t] - mean) * rs * lng[col] + lnb[col];
                eres_lds[row * 128 + col] = f2b(o);   // in-place repack (own slot)
            }
        }
    }
    __syncthreads();
    // coalesced 16B copy-out: 4 x (256 threads x 16B) = 16KB
    #pragma unroll
    for (int p = 0; p < 4; ++p) {
        ulonglong2 v = *reinterpret_cast<const ulonglong2*>((char*)A_lds + (p << 12) + tid * 16);
        *reinterpret_cast<ulonglong2*>((char*)e_dst + row0 * 256 + (p << 12) + tid * 16) = v;
    }
}

extern "C" void kernel_launch(void* const* d_in, const int* in_sizes, int n_in,
                              void* d_out, int out_size, void* d_ws, size_t ws_size,
                              hipStream_t stream) {
    (void)in_sizes; (void)n_in; (void)out_size; (void)ws_size;
    const float* node   = (const float*)d_in[0];
    const float* edge   = (const float*)d_in[1];
    const float* Wqkv_n = (const float*)d_in[2];
    const float* bqkv_n = (const float*)d_in[3];
    const float* Wqkv_e = (const float*)d_in[4];
    const float* bqkv_e = (const float*)d_in[5];
    const float* Wo     = (const float*)d_in[6];
    const float* bo     = (const float*)d_in[7];
    const float* Wn1    = (const float*)d_in[8];
    const float* bn1    = (const float*)d_in[9];
    const float* Wn2    = (const float*)d_in[10];
    const float* bn2    = (const float*)d_in[11];
    const float* ln1n_g = (const float*)d_in[12];
    const float* ln1n_b = (const float*)d_in[13];
    const float* ln2n_g = (const float*)d_in[14];
    const float* ln2n_b = (const float*)d_in[15];
    const float* We1a   = (const float*)d_in[16];
    const float* be1a   = (const float*)d_in[17];
    const float* We1b   = (const float*)d_in[18];
    const float* be1b   = (const float*)d_in[19];
    const float* We2a   = (const float*)d_in[20];
    const float* be2a   = (const float*)d_in[21];
    const float* We2b   = (const float*)d_in[22];
    const float* be2b   = (const float*)d_in[23];
    const float* ln1e_g = (const float*)d_in[24];
    const float* ln1e_b = (const float*)d_in[25];
    const float* ln2e_g = (const float*)d_in[26];
    const float* ln2e_b = (const float*)d_in[27];

    size_t off = 0;
    char* wsb = (char*)d_ws;
    auto alloc = [&](size_t bytes) -> void* {
        void* p = wsb + off;
        off = (off + bytes + 255) & ~(size_t)255;
        return p;
    };
    u16* eb0      = (u16*)alloc((size_t)RNN * 128 * 2);
    u16* eb1      = (u16*)alloc((size_t)RNN * 128 * 2);
    float* scoresp= (float*)alloc((size_t)2097152 * 4);
    float* qn     = (float*)alloc(131072 * 4);
    float* vn     = (float*)alloc(131072 * 4);
    float* attn_o = (float*)alloc(131072 * 4);
    float* nf     = (float*)alloc(131072 * 4);
    float* preS   = (float*)alloc((size_t)1024 * 512 * 4);
    float* preT   = (float*)alloc((size_t)1024 * 512 * 4);
    u16* wqT      = (u16*)alloc(3 * 16384 * 2);
    u16* wv       = (u16*)alloc(3 * 16384 * 2);
    float* bqp    = (float*)alloc(3 * 128 * 4);
    float* bvp    = (float*)alloc(3 * 128 * 4);
    u16* we1aT    = (u16*)alloc(3 * 131072ull * 2);
    u16* we1bT    = (u16*)alloc(3 * 65536 * 2);
    u16* we2aT    = (u16*)alloc(3 * 65536 * 2);
    u16* we2bT    = (u16*)alloc(3 * 65536 * 2);

    {
        dim3 g(1024, 6, 3);
        prep_weights<<<g, 256, 0, stream>>>(Wqkv_e, bqkv_e, We1a, We1b, We2a, We2b,
                                            wqT, wv, bqp, bvp, we1aT, we1bT, we2aT, we2bT);
    }
    init_e<<<2048, 256, 0, stream>>>((const float4*)edge, (ushort4*)eb0);
    init_n<<<512, 256, 0, stream>>>(node, nf);

    for (int l = 0; l < 3; ++l) {
        u16* ein  = (l & 1) ? eb1 : eb0;
        u16* eout = (l & 1) ? eb0 : eb1;
        qkvn_kernel<<<1024, 256, 0, stream>>>(nf, Wqkv_n + l * 49152, bqkv_n + l * 384, qn, vn);
        scores_kernel<<<2048, 256, 0, stream>>>(ein, wqT + l * 16384, bqp + l * 128, qn, scoresp);
        attn_pv_kernel<<<1024, 256, 0, stream>>>(scoresp, ein, vn, wv + l * 16384, bvp + l * 128, attn_o);
        node_kernel<<<1024, 256, 0, stream>>>(attn_o, nf,
                                              Wo + l * 16384, bo + l * 128,
                                              Wn1 + l * 65536, bn1 + l * 512,
                                              Wn2 + l * 65536, bn2 + l * 128,
                                              ln1n_g + l * 128, ln1n_b + l * 128,
                                              ln2n_g + l * 128, ln2n_b + l * 128);
        pre_node_kernel<<<1024, 512, 0, stream>>>(nf, We1a + (size_t)l * 262144, preS, preT);
        // e1 update: eout = LN(ein + relu(cat@We1a + pre)@We1b + b)
        fused_mlp2<4, 1><<<4096, 256, 0, stream>>>(we1aT + l * 131072, be1a + l * 512,
                                                   we1bT + l * 65536, be1b + l * 128,
                                                   ein, nullptr, ein, preS, preT,
                                                   ln1e_g + l * 128, ln1e_b + l * 128, eout);
        // e2 update (in-place): eout = LN(eout + relu(eout@We2a + b)@We2b + b)
        fused_mlp2<2, 0><<<4096, 256, 0, stream>>>(we2aT + l * 65536, be2a + l * 512,
                                                   we2bT + l * 65536, be2b + l * 128,
                                                   nullptr, eout, eout, nullptr, nullptr,
                                                   ln2e_g + l * 128, ln2e_b + l * 128, eout);
    }
    hipMemcpyAsync(d_out, nf, 131072 * sizeof(float), hipMemcpyDeviceToDevice, stream);
}